// Round 1
// baseline (436.852 us; speedup 1.0000x reference)
//
#include <hip/hip_runtime.h>
#include <stdint.h>

#define Bn 8
#define Sn 1024
#define En 1024
#define Hn 16
#define Dn 64
#define Mn (Bn*Sn)

typedef unsigned short u16;
typedef __bf16 bf16x8 __attribute__((ext_vector_type(8)));
typedef u16    u16x8  __attribute__((ext_vector_type(8)));
typedef float  f32x4  __attribute__((ext_vector_type(4)));

static __device__ __forceinline__ u16 f2bf(float x){
  union { float f; uint32_t u; } c; c.f = x;
  uint32_t r = (c.u + 0x7fffu + ((c.u >> 16) & 1u)) >> 16;
  return (u16)r;
}
static __device__ __forceinline__ float bf2f(u16 h){
  union { uint32_t u; float f; } c; c.u = ((uint32_t)h) << 16; return c.f;
}
static __device__ __forceinline__ f32x4 mfma16(bf16x8 a, bf16x8 b, f32x4 c){
  return __builtin_amdgcn_mfma_f32_16x16x32_bf16(a, b, c, 0, 0, 0);
}
static __device__ __forceinline__ void gl_lds16(const u16* g, u16* l){
  __builtin_amdgcn_global_load_lds((__attribute__((address_space(1))) void*)g,
                                   (__attribute__((address_space(3))) void*)l, 16, 0, 0);
}

// ---------------- prep: split input X into bf16 hi/lo ----------------
__global__ __launch_bounds__(256) void k_split_x(const float* __restrict__ x,
                                                 u16* __restrict__ hi,
                                                 u16* __restrict__ lo){
  int i = blockIdx.x*256 + threadIdx.x;          // one float4 per thread
  float4 v = ((const float4*)x)[i];
  ushort4 h, l;
  h.x = f2bf(v.x); l.x = f2bf(v.x - bf2f(h.x));
  h.y = f2bf(v.y); l.y = f2bf(v.y - bf2f(h.y));
  h.z = f2bf(v.z); l.z = f2bf(v.z - bf2f(h.z));
  h.w = f2bf(v.w); l.w = f2bf(v.w - bf2f(h.w));
  ((ushort4*)hi)[i] = h; ((ushort4*)lo)[i] = l;
}

// ------- prep: transpose Wq/Wk (hi/lo) and Wv (plain) to [f][e] bf16 -------
__global__ __launch_bounds__(256) void k_prep_w(const float* __restrict__ Wq,
    const float* __restrict__ Wk, const float* __restrict__ Wv,
    u16* __restrict__ qhi, u16* __restrict__ qlo,
    u16* __restrict__ khi, u16* __restrict__ klo, u16* __restrict__ vv){
  __shared__ float t[32][33];
  int tx = threadIdx.x & 31, ty = threadIdx.x >> 5;           // 32x8
  int bx = blockIdx.x & 31, by = blockIdx.x >> 5;             // f-tile, e-tile
  const float* W = (blockIdx.y == 0) ? Wq : (blockIdx.y == 1) ? Wk : Wv;
  for (int i = 0; i < 32; i += 8)
    t[ty+i][tx] = W[(size_t)(by*32+ty+i)*En + bx*32+tx];
  __syncthreads();
  for (int i = 0; i < 32; i += 8){
    float v = t[tx][ty+i];
    size_t o = (size_t)(bx*32+ty+i)*En + by*32+tx;            // Wt[f][e]
    u16 h = f2bf(v);
    if (blockIdx.y == 0){ qhi[o] = h; qlo[o] = f2bf(v - bf2f(h)); }
    else if (blockIdx.y == 1){ khi[o] = h; klo[o] = f2bf(v - bf2f(h)); }
    else vv[o] = h;
  }
}

// ---------------- prep: Wout -> bf16 (layout already [out][in] = [n][k]) ---
__global__ __launch_bounds__(256) void k_conv(const float* __restrict__ w,
                                              u16* __restrict__ o){
  int i = blockIdx.x*256 + threadIdx.x;
  float4 v = ((const float4*)w)[i];
  ushort4 h; h.x = f2bf(v.x); h.y = f2bf(v.y); h.z = f2bf(v.z); h.w = f2bf(v.w);
  ((ushort4*)o)[i] = h;
}

// ------------- split-precision GEMM for Q/K: C = (X@W) * gate*gscale -------
// A (hi/lo): [M][K] bf16, B (hi/lo): [N][K] bf16 (pre-transposed weights)
__global__ __launch_bounds__(256) void k_gemm_qk(
    const u16* __restrict__ Ahi, const u16* __restrict__ Alo,
    const u16* __restrict__ Bhi, const u16* __restrict__ Blo,
    const float* __restrict__ gate, float gscale,
    u16* __restrict__ Chi, u16* __restrict__ Clo){
  __shared__ u16 sAh[128*32], sAl[128*32], sBh[128*32], sBl[128*32];
  const int t = threadIdx.x, w = t >> 6, l = t & 63;
  const int lr = l & 15, lg = l >> 4;
  const int tn = blockIdx.x & 7, tm = blockIdx.x >> 3;
  const int m0 = tm*128, n0 = tn*128;
  const int wr = (w >> 1)*64, wc = (w & 1)*64;
  f32x4 acc[4][4] = {};
  for (int k0 = 0; k0 < En; k0 += 32){
    for (int c = 0; c < 2; c++){
      int ch  = c*256 + t;
      int row = ch >> 2;
      int xb  = (ch & 3) << 4;
      int col = k0 + ((xb ^ ((row & 3) << 4)) >> 1);   // swizzled source column
      int ldso = (c*256 + w*64) * 16;                  // wave-uniform LDS byte base
      gl_lds16(Ahi + (size_t)(m0+row)*En + col, (u16*)((char*)sAh + ldso));
      gl_lds16(Alo + (size_t)(m0+row)*En + col, (u16*)((char*)sAl + ldso));
      gl_lds16(Bhi + (size_t)(n0+row)*En + col, (u16*)((char*)sBh + ldso));
      gl_lds16(Blo + (size_t)(n0+row)*En + col, (u16*)((char*)sBl + ldso));
    }
    __syncthreads();
    bf16x8 ah[4], al[4], bh[4], bl[4];
    for (int i = 0; i < 4; i++){
      int r  = wr + i*16 + lr;
      int ob = r*64 + ((lg*16) ^ ((r & 3) << 4));
      ah[i] = *(const bf16x8*)((const char*)sAh + ob);
      al[i] = *(const bf16x8*)((const char*)sAl + ob);
      int n  = wc + i*16 + lr;
      int on = n*64 + ((lg*16) ^ ((n & 3) << 4));
      bh[i] = *(const bf16x8*)((const char*)sBh + on);
      bl[i] = *(const bf16x8*)((const char*)sBl + on);
    }
    for (int i = 0; i < 4; i++)
      for (int j = 0; j < 4; j++){
        acc[i][j] = mfma16(ah[i], bh[j], acc[i][j]);
        acc[i][j] = mfma16(ah[i], bl[j], acc[i][j]);
        acc[i][j] = mfma16(al[i], bh[j], acc[i][j]);
      }
    __syncthreads();
  }
  const int bb = m0 >> 10;   // batch (BM=128 never crosses batch boundary)
  for (int j = 0; j < 4; j++){
    int col = n0 + wc + j*16 + lr;
    float g = gate[bb*En + col] * gscale;
    for (int i = 0; i < 4; i++){
      int mbase = m0 + wr + i*16 + lg*4;
      for (int r = 0; r < 4; r++){
        float v = acc[i][j][r] * g;
        u16 h = f2bf(v);
        size_t o = (size_t)(mbase + r)*En + col;
        Chi[o] = h; Clo[o] = f2bf(v - bf2f(h));
      }
    }
  }
}

// ---- plain bf16 GEMM: MODE 0 -> bf16 C (V proj); MODE 1 -> f32 C + resid ----
template<int MODE>
__global__ __launch_bounds__(256) void k_gemm1(
    const u16* __restrict__ A, const u16* __restrict__ Bw,
    const float* __restrict__ resid, u16* __restrict__ Cb, float* __restrict__ Cf){
  __shared__ u16 sA[128*32], sB[128*32];
  const int t = threadIdx.x, w = t >> 6, l = t & 63;
  const int lr = l & 15, lg = l >> 4;
  const int tn = blockIdx.x & 7, tm = blockIdx.x >> 3;
  const int m0 = tm*128, n0 = tn*128;
  const int wr = (w >> 1)*64, wc = (w & 1)*64;
  f32x4 acc[4][4] = {};
  for (int k0 = 0; k0 < En; k0 += 32){
    for (int c = 0; c < 2; c++){
      int ch  = c*256 + t;
      int row = ch >> 2;
      int xb  = (ch & 3) << 4;
      int col = k0 + ((xb ^ ((row & 3) << 4)) >> 1);
      int ldso = (c*256 + w*64) * 16;
      gl_lds16(A  + (size_t)(m0+row)*En + col, (u16*)((char*)sA + ldso));
      gl_lds16(Bw + (size_t)(n0+row)*En + col, (u16*)((char*)sB + ldso));
    }
    __syncthreads();
    bf16x8 af[4], bf[4];
    for (int i = 0; i < 4; i++){
      int r  = wr + i*16 + lr;
      af[i] = *(const bf16x8*)((const char*)sA + r*64 + ((lg*16) ^ ((r & 3) << 4)));
      int n  = wc + i*16 + lr;
      bf[i] = *(const bf16x8*)((const char*)sB + n*64 + ((lg*16) ^ ((n & 3) << 4)));
    }
    for (int i = 0; i < 4; i++)
      for (int j = 0; j < 4; j++)
        acc[i][j] = mfma16(af[i], bf[j], acc[i][j]);
    __syncthreads();
  }
  for (int j = 0; j < 4; j++){
    int col = n0 + wc + j*16 + lr;
    for (int i = 0; i < 4; i++){
      int mbase = m0 + wr + i*16 + lg*4;
      for (int r = 0; r < 4; r++){
        size_t o = (size_t)(mbase + r)*En + col;
        if (MODE == 0) Cb[o] = f2bf(acc[i][j][r]);
        else           Cf[o] = acc[i][j][r] + resid[o];
      }
    }
  }
}

// ---------------- flash attention: TQ=64, TK=64, 4 waves per block ----------
__global__ __launch_bounds__(256) void k_attn(
    const u16* __restrict__ qhi, const u16* __restrict__ qlo,
    const u16* __restrict__ khi, const u16* __restrict__ klo,
    const u16* __restrict__ vv, u16* __restrict__ outp){
  __shared__ u16 sKh[64*64], sKl[64*64];     // [j][d], 128B rows, XOR-swizzled
  __shared__ u16 sVt[64*72];                 // V^T [d][j], padded rows (144B)
  __shared__ u16 sP[4][16*72];               // per-wave P [q][j], padded
  const int t = threadIdx.x, w = t >> 6, l = t & 63;
  const int lr = l & 15, lg = l >> 4;
  const int qt = blockIdx.x & 15, h = (blockIdx.x >> 4) & 15, b = blockIdx.x >> 8;

  // Q fragments (hi/lo) straight from global: row = this wave's 16 q-rows
  size_t qrow = (size_t)(b*Sn + qt*64 + w*16 + lr)*En + h*Dn;
  bf16x8 qh[2], ql[2];
  for (int ks = 0; ks < 2; ks++){
    qh[ks] = *(const bf16x8*)&qhi[qrow + ks*32 + lg*8];
    ql[ks] = *(const bf16x8*)&qlo[qrow + ks*32 + lg*8];
  }
  f32x4 accO[4] = {};
  float mrun[4], lrun[4];
  for (int r = 0; r < 4; r++){ mrun[r] = -1e30f; lrun[r] = 0.f; }

  for (int kt = 0; kt < Sn/64; kt++){
    int j0 = kt*64;
    // stage K hi/lo (XOR-swizzled source so linear gl_lds lands swizzled)
    for (int c = 0; c < 2; c++){
      int ch  = c*256 + t;
      int row = ch >> 3;                       // 128B per row
      int xb  = (ch & 7) << 4;
      int sx  = xb ^ ((row & 7) << 4);
      size_t g = (size_t)(b*Sn + j0 + row)*En + h*Dn + (sx >> 1);
      int ldso = (c*256 + w*64) * 16;
      gl_lds16(khi + g, (u16*)((char*)sKh + ldso));
      gl_lds16(klo + g, (u16*)((char*)sKl + ldso));
    }
    // stage V transposed via registers
    {
      int j = t & 63, d0 = (t >> 6) * 16;
      const u16* vs = &vv[(size_t)(b*Sn + j0 + j)*En + h*Dn + d0];
      u16x8 v0 = *(const u16x8*)vs;
      u16x8 v1 = *(const u16x8*)(vs + 8);
      #pragma unroll
      for (int ii = 0; ii < 8; ii++){
        sVt[(d0+ii)*72 + j]   = v0[ii];
        sVt[(d0+8+ii)*72 + j] = v1[ii];
      }
    }
    __syncthreads();
    // QK^T (3-pass split) -> scores for this wave's 16 rows x 64 cols
    f32x4 s[4] = {};
    for (int ks = 0; ks < 2; ks++)
      for (int jt = 0; jt < 4; jt++){
        int j  = jt*16 + lr;
        int ob = j*128 + ((ks*64 + lg*16) ^ ((j & 7) << 4));
        bf16x8 kh = *(const bf16x8*)((const char*)sKh + ob);
        bf16x8 kl = *(const bf16x8*)((const char*)sKl + ob);
        s[jt] = mfma16(qh[ks], kh, s[jt]);
        s[jt] = mfma16(qh[ks], kl, s[jt]);
        s[jt] = mfma16(ql[ks], kh, s[jt]);
      }
    // online softmax (rows live across 16-lane groups; cols = lanes)
    for (int r = 0; r < 4; r++){
      float m = fmaxf(fmaxf(s[0][r], s[1][r]), fmaxf(s[2][r], s[3][r]));
      for (int d = 1; d < 16; d <<= 1) m = fmaxf(m, __shfl_xor(m, d));
      float mn = fmaxf(mrun[r], m);
      float sc = __expf(mrun[r] - mn);
      mrun[r] = mn;
      float p0 = __expf(s[0][r]-mn), p1 = __expf(s[1][r]-mn);
      float p2 = __expf(s[2][r]-mn), p3 = __expf(s[3][r]-mn);
      s[0][r] = p0; s[1][r] = p1; s[2][r] = p2; s[3][r] = p3;
      float ps = p0 + p1 + p2 + p3;
      for (int d = 1; d < 16; d <<= 1) ps += __shfl_xor(ps, d);
      lrun[r] = lrun[r]*sc + ps;
      accO[0][r] *= sc; accO[1][r] *= sc; accO[2][r] *= sc; accO[3][r] *= sc;
    }
    // P -> LDS (bf16), wave-private region
    u16* P = &sP[w][0];
    for (int jt = 0; jt < 4; jt++)
      for (int r = 0; r < 4; r++)
        P[(lg*4 + r)*72 + jt*16 + lr] = f2bf(s[jt][r]);
    // PV: O[q][d] += P[q][j] * V[j][d]
    for (int js = 0; js < 2; js++){
      bf16x8 pa = *(const bf16x8*)&P[lr*72 + js*32 + lg*8];
      for (int dt = 0; dt < 4; dt++){
        bf16x8 vb = *(const bf16x8*)&sVt[(dt*16 + lr)*72 + js*32 + lg*8];
        accO[dt] = mfma16(pa, vb, accO[dt]);
      }
    }
    __syncthreads();
  }
  size_t orow0 = (size_t)(b*Sn + qt*64 + w*16);
  for (int dt = 0; dt < 4; dt++){
    int dcol = h*Dn + dt*16 + lr;
    for (int r = 0; r < 4; r++){
      float o = accO[dt][r] / lrun[r];
      outp[(orow0 + lg*4 + r)*En + dcol] = f2bf(o);
    }
  }
}

// ---------------- LayerNorm over rows of 1024 ----------------
__global__ __launch_bounds__(256) void k_ln(const float* __restrict__ res,
    const float* __restrict__ gamma, const float* __restrict__ beta,
    float* __restrict__ out){
  int row = blockIdx.x, t = threadIdx.x;
  const float* r = res + (size_t)row*En;
  float4 v = ((const float4*)r)[t];
  float s = v.x + v.y + v.z + v.w;
  float q = v.x*v.x + v.y*v.y + v.z*v.z + v.w*v.w;
  for (int d = 1; d < 64; d <<= 1){ s += __shfl_xor(s, d); q += __shfl_xor(q, d); }
  __shared__ float ss[4], sq[4];
  int w = t >> 6, l = t & 63;
  if (l == 0){ ss[w] = s; sq[w] = q; }
  __syncthreads();
  s = ss[0] + ss[1] + ss[2] + ss[3];
  q = sq[0] + sq[1] + sq[2] + sq[3];
  float mean = s * (1.f/En);
  float var  = q * (1.f/En) - mean*mean;
  float rs   = rsqrtf(var + 1e-6f);
  float4 g = ((const float4*)gamma)[t], bb = ((const float4*)beta)[t];
  float4 o;
  o.x = (v.x - mean)*rs*g.x + bb.x;
  o.y = (v.y - mean)*rs*g.y + bb.y;
  o.z = (v.z - mean)*rs*g.z + bb.z;
  o.w = (v.w - mean)*rs*g.w + bb.w;
  ((float4*)(out + (size_t)row*En))[t] = o;
}

extern "C" void kernel_launch(void* const* d_in, const int* in_sizes, int n_in,
                              void* d_out, int out_size, void* d_ws, size_t ws_size,
                              hipStream_t stream){
  (void)in_sizes; (void)n_in; (void)out_size; (void)ws_size;
  const float* X     = (const float*)d_in[0];
  const float* gQ    = (const float*)d_in[1];
  const float* gK    = (const float*)d_in[2];
  const float* Wq    = (const float*)d_in[3];
  const float* Wk    = (const float*)d_in[4];
  const float* Wv    = (const float*)d_in[5];
  const float* Wo    = (const float*)d_in[6];
  const float* gamma = (const float*)d_in[7];
  const float* beta  = (const float*)d_in[8];
  float* out = (float*)d_out;

  char* ws = (char*)d_ws;
  const size_t sz = (size_t)Mn*En*2;           // one bf16 [M][E] tensor
  u16* xhi = (u16*)(ws + 0*sz);
  u16* xlo = (u16*)(ws + 1*sz);
  u16* qh  = (u16*)(ws + 2*sz);
  u16* ql  = (u16*)(ws + 3*sz);
  u16* kh  = (u16*)(ws + 4*sz);
  u16* kl  = (u16*)(ws + 5*sz);
  u16* vb  = (u16*)(ws + 6*sz);
  u16* ao  = (u16*)(ws + 7*sz);
  float* res = (float*)(ws + 0*sz);            // overlays xhi/xlo (dead by then)
  u16* wqh = (u16*)(ws + 8*sz);
  u16* wql = wqh + (size_t)En*En;
  u16* wkh = wql + (size_t)En*En;
  u16* wkl = wkh + (size_t)En*En;
  u16* wvt = wkl + (size_t)En*En;
  u16* wob = wvt + (size_t)En*En;

  k_split_x<<<Mn*En/1024, 256, 0, stream>>>(X, xhi, xlo);
  k_prep_w<<<dim3((En/32)*(En/32), 3), 256, 0, stream>>>(Wq, Wk, Wv, wqh, wql, wkh, wkl, wvt);
  k_conv<<<En*En/1024, 256, 0, stream>>>(Wo, wob);
  // Q: fold gate*2/sqrt(64) -> g*0.25 ; K: g*2
  k_gemm_qk<<<(Mn/128)*(En/128), 256, 0, stream>>>(xhi, xlo, wqh, wql, gQ, 0.25f, qh, ql);
  k_gemm_qk<<<(Mn/128)*(En/128), 256, 0, stream>>>(xhi, xlo, wkh, wkl, gK, 2.0f, kh, kl);
  k_gemm1<0><<<(Mn/128)*(En/128), 256, 0, stream>>>(xhi, wvt, nullptr, vb, nullptr);
  k_attn<<<Bn*Hn*(Sn/64), 256, 0, stream>>>(qh, ql, kh, kl, vb, ao);
  k_gemm1<1><<<(Mn/128)*(En/128), 256, 0, stream>>>(ao, wob, X, nullptr, res);
  k_ln<<<Mn, 256, 0, stream>>>(res, gamma, beta, out);
}

// Round 2
// 419.669 us; speedup vs baseline: 1.0409x; 1.0409x over previous
//
#include <hip/hip_runtime.h>
#include <stdint.h>

#define Bn 8
#define Sn 1024
#define En 1024
#define Hn 16
#define Dn 64
#define Mn (Bn*Sn)

typedef unsigned short u16;
typedef __bf16 bf16x8 __attribute__((ext_vector_type(8)));
typedef u16    u16x8  __attribute__((ext_vector_type(8)));
typedef float  f32x4  __attribute__((ext_vector_type(4)));

static __device__ __forceinline__ u16 f2bf(float x){
  union { float f; uint32_t u; } c; c.f = x;
  uint32_t r = (c.u + 0x7fffu + ((c.u >> 16) & 1u)) >> 16;
  return (u16)r;
}
static __device__ __forceinline__ float bf2f(u16 h){
  union { uint32_t u; float f; } c; c.u = ((uint32_t)h) << 16; return c.f;
}
static __device__ __forceinline__ f32x4 mfma16(bf16x8 a, bf16x8 b, f32x4 c){
  return __builtin_amdgcn_mfma_f32_16x16x32_bf16(a, b, c, 0, 0, 0);
}
static __device__ __forceinline__ void gl_lds16(const u16* g, u16* l){
  __builtin_amdgcn_global_load_lds((__attribute__((address_space(1))) void*)g,
                                   (__attribute__((address_space(3))) void*)l, 16, 0, 0);
}

// ---------------- prep: split input X into bf16 hi/lo ----------------
__global__ __launch_bounds__(256) void k_split_x(const float* __restrict__ x,
                                                 u16* __restrict__ hi,
                                                 u16* __restrict__ lo){
  int i = blockIdx.x*256 + threadIdx.x;          // one float4 per thread
  float4 v = ((const float4*)x)[i];
  ushort4 h, l;
  h.x = f2bf(v.x); l.x = f2bf(v.x - bf2f(h.x));
  h.y = f2bf(v.y); l.y = f2bf(v.y - bf2f(h.y));
  h.z = f2bf(v.z); l.z = f2bf(v.z - bf2f(h.z));
  h.w = f2bf(v.w); l.w = f2bf(v.w - bf2f(h.w));
  ((ushort4*)hi)[i] = h; ((ushort4*)lo)[i] = l;
}

// ------- prep: transpose Wq/Wk (hi/lo) and Wv (plain) to [f][e] bf16 -------
__global__ __launch_bounds__(256) void k_prep_w(const float* __restrict__ Wq,
    const float* __restrict__ Wk, const float* __restrict__ Wv,
    u16* __restrict__ qhi, u16* __restrict__ qlo,
    u16* __restrict__ khi, u16* __restrict__ klo, u16* __restrict__ vv){
  __shared__ float t[32][33];
  int tx = threadIdx.x & 31, ty = threadIdx.x >> 5;           // 32x8
  int bx = blockIdx.x & 31, by = blockIdx.x >> 5;             // f-tile, e-tile
  const float* W = (blockIdx.y == 0) ? Wq : (blockIdx.y == 1) ? Wk : Wv;
  for (int i = 0; i < 32; i += 8)
    t[ty+i][tx] = W[(size_t)(by*32+ty+i)*En + bx*32+tx];
  __syncthreads();
  for (int i = 0; i < 32; i += 8){
    float v = t[tx][ty+i];
    size_t o = (size_t)(bx*32+ty+i)*En + by*32+tx;            // Wt[f][e]
    u16 h = f2bf(v);
    if (blockIdx.y == 0){ qhi[o] = h; qlo[o] = f2bf(v - bf2f(h)); }
    else if (blockIdx.y == 1){ khi[o] = h; klo[o] = f2bf(v - bf2f(h)); }
    else vv[o] = h;
  }
}

// ---------------- prep: Wout -> bf16 (layout already [out][in] = [n][k]) ---
__global__ __launch_bounds__(256) void k_conv(const float* __restrict__ w,
                                              u16* __restrict__ o){
  int i = blockIdx.x*256 + threadIdx.x;
  float4 v = ((const float4*)w)[i];
  ushort4 h; h.x = f2bf(v.x); h.y = f2bf(v.y); h.z = f2bf(v.z); h.w = f2bf(v.w);
  ((ushort4*)o)[i] = h;
}

// ------------- split-precision GEMM for Q/K: C = (X@W) * gate*gscale -------
__global__ __launch_bounds__(256) void k_gemm_qk(
    const u16* __restrict__ Ahi, const u16* __restrict__ Alo,
    const u16* __restrict__ Bhi, const u16* __restrict__ Blo,
    const float* __restrict__ gate, float gscale,
    u16* __restrict__ Chi, u16* __restrict__ Clo){
  __shared__ u16 sAh[128*32], sAl[128*32], sBh[128*32], sBl[128*32];
  const int t = threadIdx.x, w = t >> 6, l = t & 63;
  const int lr = l & 15, lg = l >> 4;
  const int tn = blockIdx.x & 7, tm = blockIdx.x >> 3;
  const int m0 = tm*128, n0 = tn*128;
  const int wr = (w >> 1)*64, wc = (w & 1)*64;
  f32x4 acc[4][4] = {};
  for (int k0 = 0; k0 < En; k0 += 32){
    for (int c = 0; c < 2; c++){
      int ch  = c*256 + t;
      int row = ch >> 2;
      int xb  = (ch & 3) << 4;
      int col = k0 + ((xb ^ ((row & 3) << 4)) >> 1);   // swizzled source column
      int ldso = (c*256 + w*64) * 16;                  // wave-uniform LDS byte base
      gl_lds16(Ahi + (size_t)(m0+row)*En + col, (u16*)((char*)sAh + ldso));
      gl_lds16(Alo + (size_t)(m0+row)*En + col, (u16*)((char*)sAl + ldso));
      gl_lds16(Bhi + (size_t)(n0+row)*En + col, (u16*)((char*)sBh + ldso));
      gl_lds16(Blo + (size_t)(n0+row)*En + col, (u16*)((char*)sBl + ldso));
    }
    __syncthreads();
    bf16x8 ah[4], al[4], bh[4], bl[4];
    #pragma unroll
    for (int i = 0; i < 4; i++){
      int r  = wr + i*16 + lr;
      int ob = r*64 + ((lg*16) ^ ((r & 3) << 4));
      ah[i] = *(const bf16x8*)((const char*)sAh + ob);
      al[i] = *(const bf16x8*)((const char*)sAl + ob);
      int n  = wc + i*16 + lr;
      int on = n*64 + ((lg*16) ^ ((n & 3) << 4));
      bh[i] = *(const bf16x8*)((const char*)sBh + on);
      bl[i] = *(const bf16x8*)((const char*)sBl + on);
    }
    #pragma unroll
    for (int i = 0; i < 4; i++)
      #pragma unroll
      for (int j = 0; j < 4; j++){
        acc[i][j] = mfma16(ah[i], bh[j], acc[i][j]);
        acc[i][j] = mfma16(ah[i], bl[j], acc[i][j]);
        acc[i][j] = mfma16(al[i], bh[j], acc[i][j]);
      }
    __syncthreads();
  }
  const int bb = m0 >> 10;   // batch (BM=128 never crosses batch boundary)
  #pragma unroll
  for (int j = 0; j < 4; j++){
    int col = n0 + wc + j*16 + lr;
    float g = gate[bb*En + col] * gscale;
    #pragma unroll
    for (int i = 0; i < 4; i++){
      int mbase = m0 + wr + i*16 + lg*4;
      #pragma unroll
      for (int r = 0; r < 4; r++){
        float v = acc[i][j][r] * g;
        u16 h = f2bf(v);
        size_t o = (size_t)(mbase + r)*En + col;
        Chi[o] = h; Clo[o] = f2bf(v - bf2f(h));
      }
    }
  }
}

// ---- plain bf16 GEMM: MODE 0 -> V^T per-head [B][H][D][S]; MODE 1 -> f32 + resid
template<int MODE>
__global__ __launch_bounds__(256) void k_gemm1(
    const u16* __restrict__ A, const u16* __restrict__ Bw,
    const float* __restrict__ resid, u16* __restrict__ Cb, float* __restrict__ Cf){
  __shared__ u16 sA[128*32], sB[128*32];
  const int t = threadIdx.x, w = t >> 6, l = t & 63;
  const int lr = l & 15, lg = l >> 4;
  const int tn = blockIdx.x & 7, tm = blockIdx.x >> 3;
  const int m0 = tm*128, n0 = tn*128;
  const int wr = (w >> 1)*64, wc = (w & 1)*64;
  f32x4 acc[4][4] = {};
  for (int k0 = 0; k0 < En; k0 += 32){
    for (int c = 0; c < 2; c++){
      int ch  = c*256 + t;
      int row = ch >> 2;
      int xb  = (ch & 3) << 4;
      int col = k0 + ((xb ^ ((row & 3) << 4)) >> 1);
      int ldso = (c*256 + w*64) * 16;
      gl_lds16(A  + (size_t)(m0+row)*En + col, (u16*)((char*)sA + ldso));
      gl_lds16(Bw + (size_t)(n0+row)*En + col, (u16*)((char*)sB + ldso));
    }
    __syncthreads();
    bf16x8 af[4], bf[4];
    #pragma unroll
    for (int i = 0; i < 4; i++){
      int r  = wr + i*16 + lr;
      af[i] = *(const bf16x8*)((const char*)sA + r*64 + ((lg*16) ^ ((r & 3) << 4)));
      int n  = wc + i*16 + lr;
      bf[i] = *(const bf16x8*)((const char*)sB + n*64 + ((lg*16) ^ ((n & 3) << 4)));
    }
    #pragma unroll
    for (int i = 0; i < 4; i++)
      #pragma unroll
      for (int j = 0; j < 4; j++)
        acc[i][j] = mfma16(af[i], bf[j], acc[i][j]);
    __syncthreads();
  }
  if (MODE == 0){
    // write V transposed per head: Vt[b][h][d][s], packed 4-row (s) chunks
    const int bb = m0 >> 10, s0 = (m0 & 1023) + wr;
    #pragma unroll
    for (int j = 0; j < 4; j++){
      int n = n0 + wc + j*16 + lr;
      int hh = n >> 6, d = n & 63;
      u16* dst = Cb + ((size_t)(bb*Hn + hh)*Dn + d)*Sn;
      #pragma unroll
      for (int i = 0; i < 4; i++){
        int ss = s0 + i*16 + lg*4;
        ushort4 pk;
        pk.x = f2bf(acc[i][j][0]); pk.y = f2bf(acc[i][j][1]);
        pk.z = f2bf(acc[i][j][2]); pk.w = f2bf(acc[i][j][3]);
        *(ushort4*)&dst[ss] = pk;
      }
    }
  } else {
    #pragma unroll
    for (int j = 0; j < 4; j++){
      int col = n0 + wc + j*16 + lr;
      #pragma unroll
      for (int i = 0; i < 4; i++){
        int mbase = m0 + wr + i*16 + lg*4;
        #pragma unroll
        for (int r = 0; r < 4; r++){
          size_t o = (size_t)(mbase + r)*En + col;
          Cf[o] = acc[i][j][r] + resid[o];
        }
      }
    }
  }
}

// -------- flash attention: swapped QK^T, lane-local softmax, TQ=64 ----------
__global__ __launch_bounds__(256) void k_attn(
    const u16* __restrict__ qhi, const u16* __restrict__ qlo,
    const u16* __restrict__ khi, const u16* __restrict__ klo,
    const u16* __restrict__ vt, u16* __restrict__ outp){
  __shared__ u16 sKh[64*64], sKl[64*64];   // [j][d] rows 128B, XOR-swizzled
  __shared__ u16 sVt[64*64];               // [d][j] rows 128B, XOR-swizzled
  __shared__ u16 sP[4][16*72];             // per-wave P[q][k], pad->144B rows
  const int t = threadIdx.x, w = t >> 6, l = t & 63;
  const int lr = l & 15, lg = l >> 4;
  const int qt = blockIdx.x & 15, h = (blockIdx.x >> 4) & 15, b = blockIdx.x >> 8;
  const int q0 = qt*64 + w*16;

  // Q fragments (B operand: lane holds q-row = q0+lr, k-elems d = lg*8.. )
  size_t qrow = (size_t)(b*Sn + q0 + lr)*En + h*Dn;
  bf16x8 qfh[2], qfl[2];
  #pragma unroll
  for (int ks = 0; ks < 2; ks++){
    qfh[ks] = *(const bf16x8*)&qhi[qrow + ks*32 + lg*8];
    qfl[ks] = *(const bf16x8*)&qlo[qrow + ks*32 + lg*8];
  }
  f32x4 accO[4] = {};
  float mrun = -1e30f, lrun = 0.f;
  u16* P = &sP[w][0];

  for (int kt = 0; kt < Sn/64; kt++){
    // ---- stage K hi/lo and V^T (pre-swizzled global source, linear LDS dest)
    for (int c = 0; c < 2; c++){
      int ch = c*256 + t, row = ch >> 3, slot = ch & 7;
      int jc = slot ^ (row & 7);
      int ldso = (c*256 + w*64) * 16;
      size_t gk = (size_t)(b*Sn + kt*64 + row)*En + h*Dn + jc*8;
      gl_lds16(khi + gk, (u16*)((char*)sKh + ldso));
      gl_lds16(klo + gk, (u16*)((char*)sKl + ldso));
      size_t gv = ((size_t)(b*Hn + h)*Dn + row)*Sn + kt*64 + jc*8;
      gl_lds16(vt + gv, (u16*)((char*)sVt + ldso));
    }
    __syncthreads();
    // ---- QK^T swapped: S^T tile, lane holds k = jt*16+lg*4+r for q = q0+lr
    f32x4 s[4] = {};
    #pragma unroll
    for (int ks = 0; ks < 2; ks++)
      #pragma unroll
      for (int jt = 0; jt < 4; jt++){
        int j  = jt*16 + lr;
        int ob = j*128 + ((ks*64 + lg*16) ^ ((j & 7) << 4));
        bf16x8 kf = *(const bf16x8*)((const char*)sKh + ob);
        bf16x8 kl2 = *(const bf16x8*)((const char*)sKl + ob);
        s[jt] = mfma16(kf,  qfh[ks], s[jt]);
        s[jt] = mfma16(kl2, qfh[ks], s[jt]);
        s[jt] = mfma16(kf,  qfl[ks], s[jt]);
      }
    // ---- lane-local softmax (log2 domain; scores pre-scaled by log2e)
    float m16 = fmaxf(fmaxf(fmaxf(s[0][0], s[0][1]), fmaxf(s[0][2], s[0][3])),
                      fmaxf(fmaxf(s[1][0], s[1][1]), fmaxf(s[1][2], s[1][3])));
    m16 = fmaxf(m16, fmaxf(fmaxf(fmaxf(s[2][0], s[2][1]), fmaxf(s[2][2], s[2][3])),
                           fmaxf(fmaxf(s[3][0], s[3][1]), fmaxf(s[3][2], s[3][3]))));
    m16 = fmaxf(m16, __shfl_xor(m16, 16));
    m16 = fmaxf(m16, __shfl_xor(m16, 32));
    bool defer = __all(m16 <= mrun + 8.0f);
    float mn, sc;
    if (defer){ mn = mrun; sc = 1.0f; }
    else { mn = fmaxf(mrun, m16); sc = exp2f(mrun - mn); mrun = mn; }
    float ps = 0.f;
    #pragma unroll
    for (int jt = 0; jt < 4; jt++){
      float p0 = exp2f(s[jt][0] - mn), p1 = exp2f(s[jt][1] - mn);
      float p2 = exp2f(s[jt][2] - mn), p3 = exp2f(s[jt][3] - mn);
      ps += (p0 + p1) + (p2 + p3);
      ushort4 pk; pk.x = f2bf(p0); pk.y = f2bf(p1); pk.z = f2bf(p2); pk.w = f2bf(p3);
      *(ushort4*)&P[lr*72 + jt*16 + lg*4] = pk;
    }
    ps += __shfl_xor(ps, 16);
    ps += __shfl_xor(ps, 32);
    lrun = lrun*sc + ps;
    if (!defer){
      #pragma unroll
      for (int r = 0; r < 4; r++){
        float scq = __shfl(sc, lg*4 + r);
        accO[0][r] *= scq; accO[1][r] *= scq;
        accO[2][r] *= scq; accO[3][r] *= scq;
      }
    }
    // ---- PV: O[q][d] += P[q][j] * V^T[d][j]
    #pragma unroll
    for (int js = 0; js < 2; js++){
      bf16x8 pa = *(const bf16x8*)&P[lr*72 + js*32 + lg*8];
      #pragma unroll
      for (int dt = 0; dt < 4; dt++){
        int d  = dt*16 + lr;
        int ob = d*128 + ((lg*16 + js*64) ^ ((d & 7) << 4));
        bf16x8 vb = *(const bf16x8*)((const char*)sVt + ob);
        accO[dt] = mfma16(pa, vb, accO[dt]);
      }
    }
    __syncthreads();
  }
  // ---- epilogue: normalize rows q = q0 + lg*4 + r
  float inv = 1.0f / lrun;
  float ir[4];
  #pragma unroll
  for (int r = 0; r < 4; r++) ir[r] = __shfl(inv, lg*4 + r);
  #pragma unroll
  for (int dt = 0; dt < 4; dt++){
    int dcol = h*Dn + dt*16 + lr;
    #pragma unroll
    for (int r = 0; r < 4; r++)
      outp[(size_t)(b*Sn + q0 + lg*4 + r)*En + dcol] = f2bf(accO[dt][r] * ir[r]);
  }
}

// ---------------- LayerNorm over rows of 1024 ----------------
__global__ __launch_bounds__(256) void k_ln(const float* __restrict__ res,
    const float* __restrict__ gamma, const float* __restrict__ beta,
    float* __restrict__ out){
  int row = blockIdx.x, t = threadIdx.x;
  const float* r = res + (size_t)row*En;
  float4 v = ((const float4*)r)[t];
  float s = v.x + v.y + v.z + v.w;
  float q = v.x*v.x + v.y*v.y + v.z*v.z + v.w*v.w;
  for (int d = 1; d < 64; d <<= 1){ s += __shfl_xor(s, d); q += __shfl_xor(q, d); }
  __shared__ float ss[4], sq[4];
  int w = t >> 6, l = t & 63;
  if (l == 0){ ss[w] = s; sq[w] = q; }
  __syncthreads();
  s = ss[0] + ss[1] + ss[2] + ss[3];
  q = sq[0] + sq[1] + sq[2] + sq[3];
  float mean = s * (1.f/En);
  float var  = q * (1.f/En) - mean*mean;
  float rs   = rsqrtf(var + 1e-6f);
  float4 g = ((const float4*)gamma)[t], bb = ((const float4*)beta)[t];
  float4 o;
  o.x = (v.x - mean)*rs*g.x + bb.x;
  o.y = (v.y - mean)*rs*g.y + bb.y;
  o.z = (v.z - mean)*rs*g.z + bb.z;
  o.w = (v.w - mean)*rs*g.w + bb.w;
  ((float4*)(out + (size_t)row*En))[t] = o;
}

extern "C" void kernel_launch(void* const* d_in, const int* in_sizes, int n_in,
                              void* d_out, int out_size, void* d_ws, size_t ws_size,
                              hipStream_t stream){
  (void)in_sizes; (void)n_in; (void)out_size; (void)ws_size;
  const float* X     = (const float*)d_in[0];
  const float* gQ    = (const float*)d_in[1];
  const float* gK    = (const float*)d_in[2];
  const float* Wq    = (const float*)d_in[3];
  const float* Wk    = (const float*)d_in[4];
  const float* Wv    = (const float*)d_in[5];
  const float* Wo    = (const float*)d_in[6];
  const float* gamma = (const float*)d_in[7];
  const float* beta  = (const float*)d_in[8];
  float* out = (float*)d_out;

  char* ws = (char*)d_ws;
  const size_t sz = (size_t)Mn*En*2;           // one bf16 [M][E] tensor
  u16* xhi = (u16*)(ws + 0*sz);
  u16* xlo = (u16*)(ws + 1*sz);
  u16* qh  = (u16*)(ws + 2*sz);
  u16* ql  = (u16*)(ws + 3*sz);
  u16* kh  = (u16*)(ws + 4*sz);
  u16* kl  = (u16*)(ws + 5*sz);
  u16* vb  = (u16*)(ws + 6*sz);                // V^T [B][H][D][S]
  u16* ao  = (u16*)(ws + 7*sz);
  float* res = (float*)(ws + 0*sz);            // overlays xhi/xlo (dead by then)
  u16* wqh = (u16*)(ws + 8*sz);
  u16* wql = wqh + (size_t)En*En;
  u16* wkh = wql + (size_t)En*En;
  u16* wkl = wkh + (size_t)En*En;
  u16* wvt = wkl + (size_t)En*En;
  u16* wob = wvt + (size_t)En*En;

  k_split_x<<<Mn*En/1024, 256, 0, stream>>>(X, xhi, xlo);
  k_prep_w<<<dim3((En/32)*(En/32), 3), 256, 0, stream>>>(Wq, Wk, Wv, wqh, wql, wkh, wkl, wvt);
  k_conv<<<En*En/1024, 256, 0, stream>>>(Wo, wob);
  // Q: fold gate*2/sqrt(64)*log2(e); K: gate*2  -> scores in log2 domain
  k_gemm_qk<<<(Mn/128)*(En/128), 256, 0, stream>>>(xhi, xlo, wqh, wql, gQ, 0.25f*1.4426950408889634f, qh, ql);
  k_gemm_qk<<<(Mn/128)*(En/128), 256, 0, stream>>>(xhi, xlo, wkh, wkl, gK, 2.0f, kh, kl);
  k_gemm1<0><<<(Mn/128)*(En/128), 256, 0, stream>>>(xhi, wvt, nullptr, vb, nullptr);
  k_attn<<<Bn*Hn*(Sn/64), 256, 0, stream>>>(qh, ql, kh, kl, vb, ao);
  k_gemm1<1><<<(Mn/128)*(En/128), 256, 0, stream>>>(ao, wob, X, nullptr, res);
  k_ln<<<Mn, 256, 0, stream>>>(res, gamma, beta, out);
}

// Round 4
// 320.374 us; speedup vs baseline: 1.3636x; 1.3099x over previous
//
#include <hip/hip_runtime.h>
#include <stdint.h>

#define Bn 8
#define Sn 1024
#define En 1024
#define Hn 16
#define Dn 64
#define Mn (Bn*Sn)

typedef unsigned short u16;
typedef _Float16 f16;
typedef _Float16 f16x8 __attribute__((ext_vector_type(8)));
typedef __fp16   h16x2 __attribute__((ext_vector_type(2)));
typedef float    f32x4 __attribute__((ext_vector_type(4)));

static __device__ __forceinline__ u16 f2h(float x){
  f16 h = (f16)x;                       // native RNE cast -> v_cvt_f16_f32
  union { f16 h; u16 u; } c; c.h = h; return c.u;
}
static __device__ __forceinline__ f32x4 mfma16(f16x8 a, f16x8 b, f32x4 c){
  return __builtin_amdgcn_mfma_f32_16x16x32_f16(a, b, c, 0, 0, 0);
}
static __device__ __forceinline__ void gl_lds16(const u16* g, u16* l){
  __builtin_amdgcn_global_load_lds((__attribute__((address_space(1))) void*)g,
                                   (__attribute__((address_space(3))) void*)l, 16, 0, 0);
}

// ---------------- prep: X f32 -> fp16 ----------------
__global__ __launch_bounds__(256) void k_cvt_x(const float* __restrict__ x,
                                               u16* __restrict__ o){
  int i = blockIdx.x*256 + threadIdx.x;          // one float4 per thread
  float4 v = ((const float4*)x)[i];
  ushort4 h; h.x = f2h(v.x); h.y = f2h(v.y); h.z = f2h(v.z); h.w = f2h(v.w);
  ((ushort4*)o)[i] = h;
}

// ------- prep: transpose Wq/Wk/Wv to [f][e] fp16 -------
__global__ __launch_bounds__(256) void k_prep_w(const float* __restrict__ Wq,
    const float* __restrict__ Wk, const float* __restrict__ Wv,
    u16* __restrict__ wq, u16* __restrict__ wk, u16* __restrict__ wv){
  __shared__ float t[32][33];
  int tx = threadIdx.x & 31, ty = threadIdx.x >> 5;           // 32x8
  int bx = blockIdx.x & 31, by = blockIdx.x >> 5;             // f-tile, e-tile
  const float* W = (blockIdx.y == 0) ? Wq : (blockIdx.y == 1) ? Wk : Wv;
  u16* D = (blockIdx.y == 0) ? wq : (blockIdx.y == 1) ? wk : wv;
  for (int i = 0; i < 32; i += 8)
    t[ty+i][tx] = W[(size_t)(by*32+ty+i)*En + bx*32+tx];
  __syncthreads();
  for (int i = 0; i < 32; i += 8)
    D[(size_t)(bx*32+ty+i)*En + by*32+tx] = f2h(t[tx][ty+i]);
}

// ---------------- prep: Wout -> fp16 (layout already [out][in] = [n][k]) ---
__global__ __launch_bounds__(256) void k_conv(const float* __restrict__ w,
                                              u16* __restrict__ o){
  int i = blockIdx.x*256 + threadIdx.x;
  float4 v = ((const float4*)w)[i];
  ushort4 h; h.x = f2h(v.x); h.y = f2h(v.y); h.z = f2h(v.z); h.w = f2h(v.w);
  ((ushort4*)o)[i] = h;
}

// ------------- fp16 GEMM with per-(batch,col) gate epilogue: Q/K proj -------
__global__ __launch_bounds__(256) void k_gemm_g(
    const u16* __restrict__ A, const u16* __restrict__ Bw,
    const float* __restrict__ gate, float gscale, u16* __restrict__ C){
  __shared__ u16 sA[128*32], sB[128*32];
  const int t = threadIdx.x, w = t >> 6, l = t & 63;
  const int lr = l & 15, lg = l >> 4;
  const int tn = blockIdx.x & 7, tm = blockIdx.x >> 3;
  const int m0 = tm*128, n0 = tn*128;
  const int wr = (w >> 1)*64, wc = (w & 1)*64;
  f32x4 acc[4][4] = {};
  for (int k0 = 0; k0 < En; k0 += 32){
    for (int c = 0; c < 2; c++){
      int ch  = c*256 + t;
      int row = ch >> 2;
      int xb  = (ch & 3) << 4;
      int col = k0 + ((xb ^ ((row & 3) << 4)) >> 1);   // swizzled source column
      int ldso = (c*256 + w*64) * 16;                  // wave-uniform LDS byte base
      gl_lds16(A  + (size_t)(m0+row)*En + col, (u16*)((char*)sA + ldso));
      gl_lds16(Bw + (size_t)(n0+row)*En + col, (u16*)((char*)sB + ldso));
    }
    __syncthreads();
    f16x8 af[4], bf[4];
    #pragma unroll
    for (int i = 0; i < 4; i++){
      int r  = wr + i*16 + lr;
      af[i] = *(const f16x8*)((const char*)sA + r*64 + ((lg*16) ^ ((r & 3) << 4)));
      int n  = wc + i*16 + lr;
      bf[i] = *(const f16x8*)((const char*)sB + n*64 + ((lg*16) ^ ((n & 3) << 4)));
    }
    #pragma unroll
    for (int i = 0; i < 4; i++)
      #pragma unroll
      for (int j = 0; j < 4; j++)
        acc[i][j] = mfma16(af[i], bf[j], acc[i][j]);
    __syncthreads();
  }
  const int bb = m0 >> 10;   // batch (BM=128 never crosses batch boundary)
  #pragma unroll
  for (int j = 0; j < 4; j++){
    int col = n0 + wc + j*16 + lr;
    float g = gate[bb*En + col] * gscale;
    #pragma unroll
    for (int i = 0; i < 4; i++){
      int mbase = m0 + wr + i*16 + lg*4;
      #pragma unroll
      for (int r = 0; r < 4; r++)
        C[(size_t)(mbase + r)*En + col] = f2h(acc[i][j][r] * g);
    }
  }
}

// ---- fp16 GEMM: MODE 0 -> V^T per-head [B][H][D][S]; MODE 1 -> f32 + resid
template<int MODE>
__global__ __launch_bounds__(256) void k_gemm1(
    const u16* __restrict__ A, const u16* __restrict__ Bw,
    const float* __restrict__ resid, u16* __restrict__ Cb, float* __restrict__ Cf){
  __shared__ u16 sA[128*32], sB[128*32];
  const int t = threadIdx.x, w = t >> 6, l = t & 63;
  const int lr = l & 15, lg = l >> 4;
  const int tn = blockIdx.x & 7, tm = blockIdx.x >> 3;
  const int m0 = tm*128, n0 = tn*128;
  const int wr = (w >> 1)*64, wc = (w & 1)*64;
  f32x4 acc[4][4] = {};
  for (int k0 = 0; k0 < En; k0 += 32){
    for (int c = 0; c < 2; c++){
      int ch  = c*256 + t;
      int row = ch >> 2;
      int xb  = (ch & 3) << 4;
      int col = k0 + ((xb ^ ((row & 3) << 4)) >> 1);
      int ldso = (c*256 + w*64) * 16;
      gl_lds16(A  + (size_t)(m0+row)*En + col, (u16*)((char*)sA + ldso));
      gl_lds16(Bw + (size_t)(n0+row)*En + col, (u16*)((char*)sB + ldso));
    }
    __syncthreads();
    f16x8 af[4], bf[4];
    #pragma unroll
    for (int i = 0; i < 4; i++){
      int r  = wr + i*16 + lr;
      af[i] = *(const f16x8*)((const char*)sA + r*64 + ((lg*16) ^ ((r & 3) << 4)));
      int n  = wc + i*16 + lr;
      bf[i] = *(const f16x8*)((const char*)sB + n*64 + ((lg*16) ^ ((n & 3) << 4)));
    }
    #pragma unroll
    for (int i = 0; i < 4; i++)
      #pragma unroll
      for (int j = 0; j < 4; j++)
        acc[i][j] = mfma16(af[i], bf[j], acc[i][j]);
    __syncthreads();
  }
  if (MODE == 0){
    // write V transposed per head: Vt[b][h][d][s], packed 4-col (s) chunks
    const int bb = m0 >> 10, s0 = (m0 & 1023) + wr;
    #pragma unroll
    for (int j = 0; j < 4; j++){
      int n = n0 + wc + j*16 + lr;
      int hh = n >> 6, d = n & 63;
      u16* dst = Cb + ((size_t)(bb*Hn + hh)*Dn + d)*Sn;
      #pragma unroll
      for (int i = 0; i < 4; i++){
        int ss = s0 + i*16 + lg*4;
        ushort4 pk;
        pk.x = f2h(acc[i][j][0]); pk.y = f2h(acc[i][j][1]);
        pk.z = f2h(acc[i][j][2]); pk.w = f2h(acc[i][j][3]);
        *(ushort4*)&dst[ss] = pk;
      }
    }
  } else {
    #pragma unroll
    for (int j = 0; j < 4; j++){
      int col = n0 + wc + j*16 + lr;
      #pragma unroll
      for (int i = 0; i < 4; i++){
        int mbase = m0 + wr + i*16 + lg*4;
        #pragma unroll
        for (int r = 0; r < 4; r++){
          size_t o = (size_t)(mbase + r)*En + col;
          Cf[o] = acc[i][j][r] + resid[o];
        }
      }
    }
  }
}

// -------- flash attention: fp16, swapped QK^T, lane-local softmax, TQ=64 ----
__global__ __launch_bounds__(256) void k_attn(
    const u16* __restrict__ qp, const u16* __restrict__ kp,
    const u16* __restrict__ vt, u16* __restrict__ outp){
  __shared__ u16 sK[64*64];                // [j][d] rows 128B, XOR-swizzled
  __shared__ u16 sVt[64*64];               // [d][j] rows 128B, XOR-swizzled
  __shared__ u16 sP[4][16*72];             // per-wave P[q][k], pad->144B rows
  const int t = threadIdx.x, w = t >> 6, l = t & 63;
  const int lr = l & 15, lg = l >> 4;
  const int qt = blockIdx.x & 15, h = (blockIdx.x >> 4) & 15, b = blockIdx.x >> 8;
  const int q0 = qt*64 + w*16;

  // Q fragments (B operand: lane holds q-row = q0+lr, k-elems d = lg*8.. )
  size_t qrow = (size_t)(b*Sn + q0 + lr)*En + h*Dn;
  f16x8 qf[2];
  #pragma unroll
  for (int ks = 0; ks < 2; ks++)
    qf[ks] = *(const f16x8*)&qp[qrow + ks*32 + lg*8];
  f32x4 accO[4] = {};
  float mrun = -1e30f, lrun = 0.f;
  u16* P = &sP[w][0];

  for (int kt = 0; kt < Sn/64; kt++){
    // ---- stage K and V^T (pre-swizzled global source, linear LDS dest)
    for (int c = 0; c < 2; c++){
      int ch = c*256 + t, row = ch >> 3, slot = ch & 7;
      int jc = slot ^ (row & 7);
      int ldso = (c*256 + w*64) * 16;
      size_t gk = (size_t)(b*Sn + kt*64 + row)*En + h*Dn + jc*8;
      gl_lds16(kp + gk, (u16*)((char*)sK + ldso));
      size_t gv = ((size_t)(b*Hn + h)*Dn + row)*Sn + kt*64 + jc*8;
      gl_lds16(vt + gv, (u16*)((char*)sVt + ldso));
    }
    __syncthreads();
    // ---- QK^T swapped: lane holds k = jt*16+lg*4+r for q = q0+lr
    f32x4 s[4] = {};
    __builtin_amdgcn_s_setprio(1);
    #pragma unroll
    for (int ks = 0; ks < 2; ks++)
      #pragma unroll
      for (int jt = 0; jt < 4; jt++){
        int j  = jt*16 + lr;
        int ob = j*128 + ((ks*64 + lg*16) ^ ((j & 7) << 4));
        f16x8 kf = *(const f16x8*)((const char*)sK + ob);
        s[jt] = mfma16(kf, qf[ks], s[jt]);
      }
    __builtin_amdgcn_s_setprio(0);
    // ---- lane-local softmax (log2 domain; Q pre-scaled by log2e)
    float m16 = fmaxf(fmaxf(fmaxf(s[0][0], s[0][1]), fmaxf(s[0][2], s[0][3])),
                      fmaxf(fmaxf(s[1][0], s[1][1]), fmaxf(s[1][2], s[1][3])));
    m16 = fmaxf(m16, fmaxf(fmaxf(fmaxf(s[2][0], s[2][1]), fmaxf(s[2][2], s[2][3])),
                           fmaxf(fmaxf(s[3][0], s[3][1]), fmaxf(s[3][2], s[3][3]))));
    m16 = fmaxf(m16, __shfl_xor(m16, 16));
    m16 = fmaxf(m16, __shfl_xor(m16, 32));
    bool defer = __all(m16 <= mrun + 8.0f);
    float mn, sc;
    if (defer){ mn = mrun; sc = 1.0f; }
    else { mn = fmaxf(mrun, m16); sc = exp2f(mrun - mn); mrun = mn; }
    float ps = 0.f;
    #pragma unroll
    for (int jt = 0; jt < 4; jt++){
      float p0 = exp2f(s[jt][0] - mn), p1 = exp2f(s[jt][1] - mn);
      float p2 = exp2f(s[jt][2] - mn), p3 = exp2f(s[jt][3] - mn);
      ps += (p0 + p1) + (p2 + p3);
      union { h16x2 h; uint32_t u; } ca, cb;
      ca.h = __builtin_amdgcn_cvt_pkrtz(p0, p1);
      cb.h = __builtin_amdgcn_cvt_pkrtz(p2, p3);
      uint2 pk; pk.x = ca.u; pk.y = cb.u;
      *(uint2*)&P[lr*72 + jt*16 + lg*4] = pk;
    }
    ps += __shfl_xor(ps, 16);
    ps += __shfl_xor(ps, 32);
    lrun = lrun*sc + ps;
    if (!defer){
      #pragma unroll
      for (int r = 0; r < 4; r++){
        float scq = __shfl(sc, lg*4 + r);
        accO[0][r] *= scq; accO[1][r] *= scq;
        accO[2][r] *= scq; accO[3][r] *= scq;
      }
    }
    // ---- PV: O[q][d] += P[q][j] * V^T[d][j]
    __builtin_amdgcn_s_setprio(1);
    #pragma unroll
    for (int js = 0; js < 2; js++){
      f16x8 pa = *(const f16x8*)&P[lr*72 + js*32 + lg*8];
      #pragma unroll
      for (int dt = 0; dt < 4; dt++){
        int d  = dt*16 + lr;
        int ob = d*128 + ((lg*16 + js*64) ^ ((d & 7) << 4));
        f16x8 vb = *(const f16x8*)((const char*)sVt + ob);
        accO[dt] = mfma16(pa, vb, accO[dt]);
      }
    }
    __builtin_amdgcn_s_setprio(0);
    __syncthreads();
  }
  // ---- epilogue: normalize rows q = q0 + lg*4 + r
  float inv = 1.0f / lrun;
  float ir[4];
  #pragma unroll
  for (int r = 0; r < 4; r++) ir[r] = __shfl(inv, lg*4 + r);
  #pragma unroll
  for (int dt = 0; dt < 4; dt++){
    int dcol = h*Dn + dt*16 + lr;
    #pragma unroll
    for (int r = 0; r < 4; r++)
      outp[(size_t)(b*Sn + q0 + lg*4 + r)*En + dcol] = f2h(accO[dt][r] * ir[r]);
  }
}

// ---------------- LayerNorm over rows of 1024 ----------------
__global__ __launch_bounds__(256) void k_ln(const float* __restrict__ res,
    const float* __restrict__ gamma, const float* __restrict__ beta,
    float* __restrict__ out){
  int row = blockIdx.x, t = threadIdx.x;
  const float* r = res + (size_t)row*En;
  float4 v = ((const float4*)r)[t];
  float s = v.x + v.y + v.z + v.w;
  float q = v.x*v.x + v.y*v.y + v.z*v.z + v.w*v.w;
  for (int d = 1; d < 64; d <<= 1){ s += __shfl_xor(s, d); q += __shfl_xor(q, d); }
  __shared__ float ss[4], sq[4];
  int w = t >> 6, l = t & 63;
  if (l == 0){ ss[w] = s; sq[w] = q; }
  __syncthreads();
  s = ss[0] + ss[1] + ss[2] + ss[3];
  q = sq[0] + sq[1] + sq[2] + sq[3];
  float mean = s * (1.f/En);
  float var  = q * (1.f/En) - mean*mean;
  float rs   = rsqrtf(var + 1e-6f);
  float4 g = ((const float4*)gamma)[t], bb = ((const float4*)beta)[t];
  float4 o;
  o.x = (v.x - mean)*rs*g.x + bb.x;
  o.y = (v.y - mean)*rs*g.y + bb.y;
  o.z = (v.z - mean)*rs*g.z + bb.z;
  o.w = (v.w - mean)*rs*g.w + bb.w;
  ((float4*)(out + (size_t)row*En))[t] = o;
}

extern "C" void kernel_launch(void* const* d_in, const int* in_sizes, int n_in,
                              void* d_out, int out_size, void* d_ws, size_t ws_size,
                              hipStream_t stream){
  (void)in_sizes; (void)n_in; (void)out_size; (void)ws_size;
  const float* X     = (const float*)d_in[0];
  const float* gQ    = (const float*)d_in[1];
  const float* gK    = (const float*)d_in[2];
  const float* Wq    = (const float*)d_in[3];
  const float* Wk    = (const float*)d_in[4];
  const float* Wv    = (const float*)d_in[5];
  const float* Wo    = (const float*)d_in[6];
  const float* gamma = (const float*)d_in[7];
  const float* beta  = (const float*)d_in[8];
  float* out = (float*)d_out;

  char* ws = (char*)d_ws;
  const size_t sz = (size_t)Mn*En*2;           // one fp16 [M][E] tensor (16MB)
  u16* xh = (u16*)(ws + 0*sz);
  u16* qh = (u16*)(ws + 1*sz);
  u16* kh = (u16*)(ws + 2*sz);
  u16* vb = (u16*)(ws + 3*sz);                 // V^T [B][H][D][S]
  u16* ao = (u16*)(ws + 4*sz);
  float* res = (float*)(ws + 0*sz);            // overlays xh+qh (dead by then)
  u16* wq = (u16*)(ws + 5*sz);
  u16* wk = wq + (size_t)En*En;
  u16* wv = wk + (size_t)En*En;
  u16* wo = wv + (size_t)En*En;

  k_cvt_x<<<Mn*En/1024, 256, 0, stream>>>(X, xh);
  k_prep_w<<<dim3((En/32)*(En/32), 3), 256, 0, stream>>>(Wq, Wk, Wv, wq, wk, wv);
  k_conv<<<En*En/1024, 256, 0, stream>>>(Wo, wo);
  // Q: fold gate*2/sqrt(64)*log2(e); K: gate*2  -> scores in log2 domain
  k_gemm_g<<<(Mn/128)*(En/128), 256, 0, stream>>>(xh, wq, gQ, 0.25f*1.4426950408889634f, qh);
  k_gemm_g<<<(Mn/128)*(En/128), 256, 0, stream>>>(xh, wk, gK, 2.0f, kh);
  k_gemm1<0><<<(Mn/128)*(En/128), 256, 0, stream>>>(xh, wv, nullptr, vb, nullptr);
  k_attn<<<Bn*Hn*(Sn/64), 256, 0, stream>>>(qh, kh, vb, ao);
  k_gemm1<1><<<(Mn/128)*(En/128), 256, 0, stream>>>(ao, wo, X, nullptr, res);
  k_ln<<<Mn, 256, 0, stream>>>(res, gamma, beta, out);
}

// Round 6
// 297.001 us; speedup vs baseline: 1.4709x; 1.0787x over previous
//
#include <hip/hip_runtime.h>
#include <stdint.h>

#define Bn 8
#define Sn 1024
#define En 1024
#define Hn 16
#define Dn 64
#define Mn (Bn*Sn)

typedef unsigned short u16;
typedef _Float16 f16;
typedef _Float16 f16x8 __attribute__((ext_vector_type(8)));
typedef __fp16   h16x2 __attribute__((ext_vector_type(2)));
typedef float    f32x4 __attribute__((ext_vector_type(4)));

#define VMCNT(n) asm volatile("s_waitcnt vmcnt(" #n ")" ::: "memory")
#define CFENCE() asm volatile("" ::: "memory")

static __device__ __forceinline__ u16 f2h(float x){
  f16 h = (f16)x;                       // native RNE cast -> v_cvt_f16_f32
  union { f16 h; u16 u; } c; c.h = h; return c.u;
}
static __device__ __forceinline__ f32x4 mfma16(f16x8 a, f16x8 b, f32x4 c){
  return __builtin_amdgcn_mfma_f32_16x16x32_f16(a, b, c, 0, 0, 0);
}
static __device__ __forceinline__ void gl_lds16(const u16* g, u16* l){
  __builtin_amdgcn_global_load_lds((__attribute__((address_space(1))) void*)g,
                                   (__attribute__((address_space(3))) void*)l, 16, 0, 0);
}

// ---------------- prep: X f32 -> fp16 ----------------
__global__ __launch_bounds__(256) void k_cvt_x(const float* __restrict__ x,
                                               u16* __restrict__ o){
  int i = blockIdx.x*256 + threadIdx.x;          // one float4 per thread
  float4 v = ((const float4*)x)[i];
  ushort4 h; h.x = f2h(v.x); h.y = f2h(v.y); h.z = f2h(v.z); h.w = f2h(v.w);
  ((ushort4*)o)[i] = h;
}

// ------- prep: transpose Wq/Wk/Wv to [f][e] fp16 -------
__global__ __launch_bounds__(256) void k_prep_w(const float* __restrict__ Wq,
    const float* __restrict__ Wk, const float* __restrict__ Wv,
    u16* __restrict__ wq, u16* __restrict__ wk, u16* __restrict__ wv){
  __shared__ float t[32][33];
  int tx = threadIdx.x & 31, ty = threadIdx.x >> 5;           // 32x8
  int bx = blockIdx.x & 31, by = blockIdx.x >> 5;             // f-tile, e-tile
  const float* W = (blockIdx.y == 0) ? Wq : (blockIdx.y == 1) ? Wk : Wv;
  u16* D = (blockIdx.y == 0) ? wq : (blockIdx.y == 1) ? wk : wv;
  for (int i = 0; i < 32; i += 8)
    t[ty+i][tx] = W[(size_t)(by*32+ty+i)*En + bx*32+tx];
  __syncthreads();
  for (int i = 0; i < 32; i += 8)
    D[(size_t)(bx*32+ty+i)*En + by*32+tx] = f2h(t[tx][ty+i]);
}

// ---------------- prep: Wout -> fp16 (layout already [out][in] = [n][k]) ---
__global__ __launch_bounds__(256) void k_conv(const float* __restrict__ w,
                                              u16* __restrict__ o){
  int i = blockIdx.x*256 + threadIdx.x;
  float4 v = ((const float4*)w)[i];
  ushort4 h; h.x = f2h(v.x); h.y = f2h(v.y); h.z = f2h(v.z); h.w = f2h(v.w);
  ((ushort4*)o)[i] = h;
}

// ---- fused QKV projection GEMM: B = [3072][1024] (Wq^T|Wk^T|Wv^T stacked) ----
// n0 < 1024 -> Q (gate*0.25*log2e), < 2048 -> K (gate*2), else V^T per-head store
__global__ __launch_bounds__(256) void k_gemm_qkv(
    const u16* __restrict__ A, const u16* __restrict__ Bw,
    const float* __restrict__ gQ, const float* __restrict__ gK,
    u16* __restrict__ Cq, u16* __restrict__ Ck, u16* __restrict__ Vt){
  __shared__ u16 sA[128*32], sB[128*32];
  const int t = threadIdx.x, w = t >> 6, l = t & 63;
  const int lr = l & 15, lg = l >> 4;
  const int tn = blockIdx.x % 24, tm = blockIdx.x / 24;
  const int m0 = tm*128, n0 = tn*128;
  const int wr = (w >> 1)*64, wc = (w & 1)*64;
  f32x4 acc[4][4] = {};
  for (int k0 = 0; k0 < En; k0 += 32){
    for (int c = 0; c < 2; c++){
      int ch  = c*256 + t;
      int row = ch >> 2;
      int xb  = (ch & 3) << 4;
      int col = k0 + ((xb ^ ((row & 3) << 4)) >> 1);   // swizzled source column
      int ldso = (c*256 + w*64) * 16;                  // wave-uniform LDS byte base
      gl_lds16(A  + (size_t)(m0+row)*En + col, (u16*)((char*)sA + ldso));
      gl_lds16(Bw + (size_t)(n0+row)*En + col, (u16*)((char*)sB + ldso));
    }
    __syncthreads();
    f16x8 af[4], bf[4];
    #pragma unroll
    for (int i = 0; i < 4; i++){
      int r  = wr + i*16 + lr;
      af[i] = *(const f16x8*)((const char*)sA + r*64 + ((lg*16) ^ ((r & 3) << 4)));
      int n  = wc + i*16 + lr;
      bf[i] = *(const f16x8*)((const char*)sB + n*64 + ((lg*16) ^ ((n & 3) << 4)));
    }
    __builtin_amdgcn_s_setprio(1);
    #pragma unroll
    for (int i = 0; i < 4; i++)
      #pragma unroll
      for (int j = 0; j < 4; j++)
        acc[i][j] = mfma16(af[i], bf[j], acc[i][j]);
    __builtin_amdgcn_s_setprio(0);
    __syncthreads();
  }
  const int bb = m0 >> 10;   // batch (BM=128 never crosses batch boundary)
  const int sel = n0 >> 10;  // 0=Q 1=K 2=V (uniform per block)
  if (sel < 2){
    const float* gate = sel ? gK : gQ;
    const float gs = sel ? 2.0f : 0.25f*1.4426950408889634f;
    u16* C = sel ? Ck : Cq;
    #pragma unroll
    for (int j = 0; j < 4; j++){
      int col = (n0 & 1023) + wc + j*16 + lr;
      float g = gate[bb*En + col] * gs;
      #pragma unroll
      for (int i = 0; i < 4; i++){
        int mbase = m0 + wr + i*16 + lg*4;
        #pragma unroll
        for (int r = 0; r < 4; r++)
          C[(size_t)(mbase + r)*En + col] = f2h(acc[i][j][r] * g);
      }
    }
  } else {
    const int s0 = (m0 & 1023) + wr;
    #pragma unroll
    for (int j = 0; j < 4; j++){
      int nn = (n0 - 2048) + wc + j*16 + lr;
      int hh = nn >> 6, d = nn & 63;
      u16* dst = Vt + ((size_t)(bb*Hn + hh)*Dn + d)*Sn;
      #pragma unroll
      for (int i = 0; i < 4; i++){
        int ss = s0 + i*16 + lg*4;
        ushort4 pk;
        pk.x = f2h(acc[i][j][0]); pk.y = f2h(acc[i][j][1]);
        pk.z = f2h(acc[i][j][2]); pk.w = f2h(acc[i][j][3]);
        *(ushort4*)&dst[ss] = pk;
      }
    }
  }
}

// ---------------- out-proj GEMM: f32 out + residual ----------------
__global__ __launch_bounds__(256) void k_gemm_out(
    const u16* __restrict__ A, const u16* __restrict__ Bw,
    const float* __restrict__ resid, float* __restrict__ Cf){
  __shared__ u16 sA[128*32], sB[128*32];
  const int t = threadIdx.x, w = t >> 6, l = t & 63;
  const int lr = l & 15, lg = l >> 4;
  const int tn = blockIdx.x & 7, tm = blockIdx.x >> 3;
  const int m0 = tm*128, n0 = tn*128;
  const int wr = (w >> 1)*64, wc = (w & 1)*64;
  f32x4 acc[4][4] = {};
  for (int k0 = 0; k0 < En; k0 += 32){
    for (int c = 0; c < 2; c++){
      int ch  = c*256 + t;
      int row = ch >> 2;
      int xb  = (ch & 3) << 4;
      int col = k0 + ((xb ^ ((row & 3) << 4)) >> 1);
      int ldso = (c*256 + w*64) * 16;
      gl_lds16(A  + (size_t)(m0+row)*En + col, (u16*)((char*)sA + ldso));
      gl_lds16(Bw + (size_t)(n0+row)*En + col, (u16*)((char*)sB + ldso));
    }
    __syncthreads();
    f16x8 af[4], bf[4];
    #pragma unroll
    for (int i = 0; i < 4; i++){
      int r  = wr + i*16 + lr;
      af[i] = *(const f16x8*)((const char*)sA + r*64 + ((lg*16) ^ ((r & 3) << 4)));
      int n  = wc + i*16 + lr;
      bf[i] = *(const f16x8*)((const char*)sB + n*64 + ((lg*16) ^ ((n & 3) << 4)));
    }
    __builtin_amdgcn_s_setprio(1);
    #pragma unroll
    for (int i = 0; i < 4; i++)
      #pragma unroll
      for (int j = 0; j < 4; j++)
        acc[i][j] = mfma16(af[i], bf[j], acc[i][j]);
    __builtin_amdgcn_s_setprio(0);
    __syncthreads();
  }
  #pragma unroll
  for (int j = 0; j < 4; j++){
    int col = n0 + wc + j*16 + lr;
    #pragma unroll
    for (int i = 0; i < 4; i++){
      int mbase = m0 + wr + i*16 + lg*4;
      #pragma unroll
      for (int r = 0; r < 4; r++){
        size_t o = (size_t)(mbase + r)*En + col;
        Cf[o] = acc[i][j][r] + resid[o];
      }
    }
  }
}

// -------- flash attention: 8 waves, TQ=128, dbuf K/V + counted vmcnt --------
// blockIdx: qt = bid>>7 (q-tile), hb = bid&127 -> h, b. All 8 qt of a (b,h)
// share bid%8 -> same XCD -> K/V stays in one L2 (4MB = 16 pairs * 256KB).
__global__ __launch_bounds__(512) void k_attn(
    const u16* __restrict__ qp, const u16* __restrict__ kp,
    const u16* __restrict__ vt, u16* __restrict__ outp){
  __shared__ u16 sK[2][64*64];             // [j][d] rows 128B, XOR-swizzled
  __shared__ u16 sVt[2][64*64];            // [d][j] rows 128B, XOR-swizzled
  __shared__ u16 sP[8][16*72];             // per-wave P[q][k], pad->144B rows
  const int t = threadIdx.x, w = t >> 6, l = t & 63;
  const int lr = l & 15, lg = l >> 4;
  const int qt = blockIdx.x >> 7, hb = blockIdx.x & 127;
  const int h = hb & 15, b = hb >> 4;
  const int q0 = qt*128 + w*16;

  // staging addresses: 512 threads cover one 64x64 fp16 tile per gl_lds each
  const int srow = t >> 3, slot = t & 7, jc = slot ^ (srow & 7);
  const size_t gkbase = (size_t)(b*Sn + srow)*En + h*Dn + jc*8;    // + kt*64*En
  const size_t gvbase = ((size_t)(b*Hn + h)*Dn + srow)*Sn + jc*8;  // + kt*64

#define STAGE(buf, kt_) do { \
    gl_lds16(kp + gkbase + (size_t)(kt_)*64*En, (u16*)((char*)sK[buf] + w*1024)); \
    gl_lds16(vt + gvbase + (kt_)*64,            (u16*)((char*)sVt[buf] + w*1024)); \
  } while (0)

  // Q fragments (B operand: lane holds q-row = q0+lr, k-elems d = lg*8.. )
  size_t qrow = (size_t)(b*Sn + q0 + lr)*En + h*Dn;
  f16x8 qf[2];
  #pragma unroll
  for (int ks = 0; ks < 2; ks++)
    qf[ks] = *(const f16x8*)&qp[qrow + ks*32 + lg*8];
  f32x4 accO[4] = {};
  float mrun = -1e30f, lrun = 0.f;
  u16* P = &sP[w][0];

  STAGE(0, 0);
  for (int kt = 0; kt < Sn/64; kt++){
    const int cur = kt & 1;
    if (kt < Sn/64 - 1){ STAGE(cur^1, kt+1); VMCNT(2); }
    else               { VMCNT(0); }
    __builtin_amdgcn_s_barrier();
    CFENCE();
    // ---- QK^T swapped: lane holds k = jt*16+lg*4+r for q = q0+lr
    f32x4 s[4] = {};
    __builtin_amdgcn_s_setprio(1);
    #pragma unroll
    for (int ks = 0; ks < 2; ks++)
      #pragma unroll
      for (int jt = 0; jt < 4; jt++){
        int j  = jt*16 + lr;
        int ob = j*128 + ((ks*64 + lg*16) ^ ((j & 7) << 4));
        f16x8 kf = *(const f16x8*)((const char*)sK[cur] + ob);
        s[jt] = mfma16(kf, qf[ks], s[jt]);
      }
    __builtin_amdgcn_s_setprio(0);
    // ---- lane-local softmax (log2 domain; Q pre-scaled by log2e)
    float m16 = fmaxf(fmaxf(fmaxf(s[0][0], s[0][1]), fmaxf(s[0][2], s[0][3])),
                      fmaxf(fmaxf(s[1][0], s[1][1]), fmaxf(s[1][2], s[1][3])));
    m16 = fmaxf(m16, fmaxf(fmaxf(fmaxf(s[2][0], s[2][1]), fmaxf(s[2][2], s[2][3])),
                           fmaxf(fmaxf(s[3][0], s[3][1]), fmaxf(s[3][2], s[3][3]))));
    m16 = fmaxf(m16, __shfl_xor(m16, 16));
    m16 = fmaxf(m16, __shfl_xor(m16, 32));
    bool defer = __all(m16 <= mrun + 8.0f);
    float mn, sc;
    if (defer){ mn = mrun; sc = 1.0f; }
    else { mn = fmaxf(mrun, m16); sc = exp2f(mrun - mn); mrun = mn; }
    float ps = 0.f;
    #pragma unroll
    for (int jt = 0; jt < 4; jt++){
      float p0 = exp2f(s[jt][0] - mn), p1 = exp2f(s[jt][1] - mn);
      float p2 = exp2f(s[jt][2] - mn), p3 = exp2f(s[jt][3] - mn);
      ps += (p0 + p1) + (p2 + p3);
      union { h16x2 h; uint32_t u; } ca, cb;
      ca.h = __builtin_amdgcn_cvt_pkrtz(p0, p1);
      cb.h = __builtin_amdgcn_cvt_pkrtz(p2, p3);
      uint2 pk; pk.x = ca.u; pk.y = cb.u;
      *(uint2*)&P[lr*72 + jt*16 + lg*4] = pk;
    }
    ps += __shfl_xor(ps, 16);
    ps += __shfl_xor(ps, 32);
    lrun = lrun*sc + ps;
    if (!defer){
      #pragma unroll
      for (int r = 0; r < 4; r++){
        float scq = __shfl(sc, lg*4 + r);
        accO[0][r] *= scq; accO[1][r] *= scq;
        accO[2][r] *= scq; accO[3][r] *= scq;
      }
    }
    // ---- PV: O[q][d] += P[q][j] * V^T[d][j]
    __builtin_amdgcn_s_setprio(1);
    #pragma unroll
    for (int js = 0; js < 2; js++){
      f16x8 pa = *(const f16x8*)&P[lr*72 + js*32 + lg*8];
      #pragma unroll
      for (int dt = 0; dt < 4; dt++){
        int d  = dt*16 + lr;
        int ob = d*128 + ((lg*16 + js*64) ^ ((d & 7) << 4));
        f16x8 vb = *(const f16x8*)((const char*)sVt[cur] + ob);
        accO[dt] = mfma16(pa, vb, accO[dt]);
      }
    }
    __builtin_amdgcn_s_setprio(0);
    if (kt < Sn/64 - 1){
      CFENCE();
      __builtin_amdgcn_s_barrier();   // buf[cur] free for STAGE at next iter
    }
  }
#undef STAGE
  // ---- epilogue: normalize rows q = q0 + lg*4 + r
  float inv = 1.0f / lrun;
  float ir[4];
  #pragma unroll
  for (int r = 0; r < 4; r++) ir[r] = __shfl(inv, lg*4 + r);
  #pragma unroll
  for (int dt = 0; dt < 4; dt++){
    int dcol = h*Dn + dt*16 + lr;
    #pragma unroll
    for (int r = 0; r < 4; r++)
      outp[(size_t)(b*Sn + q0 + lg*4 + r)*En + dcol] = f2h(accO[dt][r] * ir[r]);
  }
}

// ---------------- LayerNorm over rows of 1024 ----------------
__global__ __launch_bounds__(256) void k_ln(const float* __restrict__ res,
    const float* __restrict__ gamma, const float* __restrict__ beta,
    float* __restrict__ out){
  int row = blockIdx.x, t = threadIdx.x;
  const float* r = res + (size_t)row*En;
  float4 v = ((const float4*)r)[t];
  float s = v.x + v.y + v.z + v.w;
  float q = v.x*v.x + v.y*v.y + v.z*v.z + v.w*v.w;
  for (int d = 1; d < 64; d <<= 1){ s += __shfl_xor(s, d); q += __shfl_xor(q, d); }
  __shared__ float ss[4], sq[4];
  int w = t >> 6, l = t & 63;
  if (l == 0){ ss[w] = s; sq[w] = q; }
  __syncthreads();
  s = ss[0] + ss[1] + ss[2] + ss[3];
  q = sq[0] + sq[1] + sq[2] + sq[3];
  float mean = s * (1.f/En);
  float var  = q * (1.f/En) - mean*mean;
  float rs   = rsqrtf(var + 1e-6f);
  float4 g = ((const float4*)gamma)[t], bb = ((const float4*)beta)[t];
  float4 o;
  o.x = (v.x - mean)*rs*g.x + bb.x;
  o.y = (v.y - mean)*rs*g.y + bb.y;
  o.z = (v.z - mean)*rs*g.z + bb.z;
  o.w = (v.w - mean)*rs*g.w + bb.w;
  ((float4*)(out + (size_t)row*En))[t] = o;
}

extern "C" void kernel_launch(void* const* d_in, const int* in_sizes, int n_in,
                              void* d_out, int out_size, void* d_ws, size_t ws_size,
                              hipStream_t stream){
  (void)in_sizes; (void)n_in; (void)out_size; (void)ws_size;
  const float* X     = (const float*)d_in[0];
  const float* gQ    = (const float*)d_in[1];
  const float* gK    = (const float*)d_in[2];
  const float* Wq    = (const float*)d_in[3];
  const float* Wk    = (const float*)d_in[4];
  const float* Wv    = (const float*)d_in[5];
  const float* Wo    = (const float*)d_in[6];
  const float* gamma = (const float*)d_in[7];
  const float* beta  = (const float*)d_in[8];
  float* out = (float*)d_out;

  char* ws = (char*)d_ws;
  const size_t sz = (size_t)Mn*En*2;           // one fp16 [M][E] tensor (16MB)
  u16* xh = (u16*)(ws + 0*sz);
  u16* qh = (u16*)(ws + 1*sz);
  u16* kh = (u16*)(ws + 2*sz);
  u16* vb = (u16*)(ws + 3*sz);                 // V^T [B][H][D][S]
  u16* ao = (u16*)(ws + 4*sz);
  float* res = (float*)(ws + 0*sz);            // overlays xh+qh (dead by then)
  u16* wq = (u16*)(ws + 5*sz);                 // [3072][1024] fp16: Wq^T|Wk^T|Wv^T
  u16* wk = wq + (size_t)En*En;
  u16* wv = wk + (size_t)En*En;
  u16* wo = wv + (size_t)En*En;

  k_cvt_x<<<Mn*En/1024, 256, 0, stream>>>(X, xh);
  k_prep_w<<<dim3((En/32)*(En/32), 3), 256, 0, stream>>>(Wq, Wk, Wv, wq, wk, wv);
  k_conv<<<En*En/1024, 256, 0, stream>>>(Wo, wo);
  // fused QKV: Q gate*2/sqrt(64)*log2(e), K gate*2, V -> per-head V^T
  k_gemm_qkv<<<(Mn/128)*(3*En/128), 256, 0, stream>>>(xh, wq, gQ, gK, qh, kh, vb);
  k_attn<<<(Sn/128)*Hn*Bn, 512, 0, stream>>>(qh, kh, vb, ao);
  k_gemm_out<<<(Mn/128)*(En/128), 256, 0, stream>>>(ao, wo, X, res);
  k_ln<<<Mn, 256, 0, stream>>>(res, gamma, beta, out);
}

// Round 7
// 276.675 us; speedup vs baseline: 1.5789x; 1.0735x over previous
//
#include <hip/hip_runtime.h>
#include <stdint.h>

#define Bn 8
#define Sn 1024
#define En 1024
#define Hn 16
#define Dn 64
#define Mn (Bn*Sn)

typedef unsigned short u16;
typedef _Float16 f16;
typedef _Float16 f16x8 __attribute__((ext_vector_type(8)));
typedef __fp16   h16x2 __attribute__((ext_vector_type(2)));
typedef float    f32x4 __attribute__((ext_vector_type(4)));

static __device__ __forceinline__ u16 f2h(float x){
  f16 h = (f16)x;                       // native RNE cast -> v_cvt_f16_f32
  union { f16 h; u16 u; } c; c.h = h; return c.u;
}
static __device__ __forceinline__ float h2f(u16 u){
  union { u16 u; f16 h; } c; c.u = u; return (float)c.h;
}
static __device__ __forceinline__ float fexp2(float x){
  float r; asm("v_exp_f32 %0, %1" : "=v"(r) : "v"(x)); return r;
}
static __device__ __forceinline__ f32x4 mfma16(f16x8 a, f16x8 b, f32x4 c){
  return __builtin_amdgcn_mfma_f32_16x16x32_f16(a, b, c, 0, 0, 0);
}
static __device__ __forceinline__ void gl_lds16(const u16* g, u16* l){
  __builtin_amdgcn_global_load_lds((__attribute__((address_space(1))) void*)g,
                                   (__attribute__((address_space(3))) void*)l, 16, 0, 0);
}

// ------------- fused prep: X->fp16 | Wo->fp16 | Wq/Wk/Wv transpose ----------
// blocks [0,8192): cvt X ; [8192,9216): cvt Wo ; [9216,12288): transpose QKV
__global__ __launch_bounds__(256) void k_prep(const float* __restrict__ X,
    const float* __restrict__ Wq, const float* __restrict__ Wk,
    const float* __restrict__ Wv, const float* __restrict__ Wo,
    u16* __restrict__ xh, u16* __restrict__ wq, u16* __restrict__ wk,
    u16* __restrict__ wv, u16* __restrict__ wo){
  __shared__ float tsh[32][33];
  const int bid = blockIdx.x, tid = threadIdx.x;
  if (bid < 9216){
    const float* src = (bid < 8192) ? X : Wo;
    u16* dst = (bid < 8192) ? xh : wo;
    int i = (bid < 8192 ? bid : bid - 8192)*256 + tid;
    float4 v = ((const float4*)src)[i];
    ushort4 h; h.x = f2h(v.x); h.y = f2h(v.y); h.z = f2h(v.z); h.w = f2h(v.w);
    ((ushort4*)dst)[i] = h;
  } else {
    int pb = bid - 9216;
    int sel = pb >> 10, inner = pb & 1023;
    int bx = inner & 31, by = inner >> 5;
    int tx = tid & 31, ty = tid >> 5;
    const float* W = (sel == 0) ? Wq : (sel == 1) ? Wk : Wv;
    u16* D = (sel == 0) ? wq : (sel == 1) ? wk : wv;
    for (int i = 0; i < 32; i += 8)
      tsh[ty+i][tx] = W[(size_t)(by*32+ty+i)*En + bx*32+tx];
    __syncthreads();
    for (int i = 0; i < 32; i += 8)
      D[(size_t)(bx*32+ty+i)*En + by*32+tx] = f2h(tsh[tx][ty+i]);
  }
}

// ---- fused QKV projection GEMM: B = [3072][1024] (Wq^T|Wk^T|Wv^T stacked) ----
// single-barrier dbuf: stage(next) overlaps compute(cur)
__global__ __launch_bounds__(256) void k_gemm_qkv(
    const u16* __restrict__ A, const u16* __restrict__ Bw,
    const float* __restrict__ gQ, const float* __restrict__ gK,
    u16* __restrict__ Cq, u16* __restrict__ Ck, u16* __restrict__ Vt){
  __shared__ u16 sA[2*128*32], sB[2*128*32];
  const int t = threadIdx.x, w = t >> 6, l = t & 63;
  const int lr = l & 15, lg = l >> 4;
  const int tn = blockIdx.x % 24, tm = blockIdx.x / 24;
  const int m0 = tm*128, n0 = tn*128;
  const int wr = (w >> 1)*64, wc = (w & 1)*64;
  f32x4 acc[4][4] = {};

#define GSTAGE(buf, k0_) do { \
    for (int c = 0; c < 2; c++){ \
      int ch  = c*256 + t; \
      int row = ch >> 2; \
      int xb  = (ch & 3) << 4; \
      int col = (k0_) + ((xb ^ ((row & 3) << 4)) >> 1); \
      int ldso = (buf)*8192 + (c*256 + w*64)*16; \
      gl_lds16(A  + (size_t)(m0+row)*En + col, (u16*)((char*)sA + ldso)); \
      gl_lds16(Bw + (size_t)(n0+row)*En + col, (u16*)((char*)sB + ldso)); \
    } } while (0)

  GSTAGE(0, 0);
  __syncthreads();
  for (int kt = 0; kt < En/32; kt++){
    const int cur = kt & 1;
    if (kt < En/32 - 1) GSTAGE(cur^1, (kt+1)*32);
    f16x8 af[4], bf[4];
    #pragma unroll
    for (int i = 0; i < 4; i++){
      int r  = wr + i*16 + lr;
      af[i] = *(const f16x8*)((const char*)sA + cur*8192 + r*64 + ((lg*16) ^ ((r & 3) << 4)));
      int n  = wc + i*16 + lr;
      bf[i] = *(const f16x8*)((const char*)sB + cur*8192 + n*64 + ((lg*16) ^ ((n & 3) << 4)));
    }
    __builtin_amdgcn_s_setprio(1);
    #pragma unroll
    for (int i = 0; i < 4; i++)
      #pragma unroll
      for (int j = 0; j < 4; j++)
        acc[i][j] = mfma16(af[i], bf[j], acc[i][j]);
    __builtin_amdgcn_s_setprio(0);
    __syncthreads();
  }
#undef GSTAGE
  const int bb = m0 >> 10;   // batch (BM=128 never crosses batch boundary)
  const int sel = n0 >> 10;  // 0=Q 1=K 2=V (uniform per block)
  if (sel < 2){
    const float* gate = sel ? gK : gQ;
    const float gs = sel ? 2.0f : 0.25f*1.4426950408889634f;
    u16* C = sel ? Ck : Cq;
    #pragma unroll
    for (int j = 0; j < 4; j++){
      int col = (n0 & 1023) + wc + j*16 + lr;
      float g = gate[bb*En + col] * gs;
      #pragma unroll
      for (int i = 0; i < 4; i++){
        int mbase = m0 + wr + i*16 + lg*4;
        #pragma unroll
        for (int r = 0; r < 4; r++)
          C[(size_t)(mbase + r)*En + col] = f2h(acc[i][j][r] * g);
      }
    }
  } else {
    const int s0 = (m0 & 1023) + wr;
    #pragma unroll
    for (int j = 0; j < 4; j++){
      int nn = (n0 - 2048) + wc + j*16 + lr;
      int hh = nn >> 6, d = nn & 63;
      u16* dst = Vt + ((size_t)(bb*Hn + hh)*Dn + d)*Sn;
      #pragma unroll
      for (int i = 0; i < 4; i++){
        int ss = s0 + i*16 + lg*4;
        ushort4 pk;
        pk.x = f2h(acc[i][j][0]); pk.y = f2h(acc[i][j][1]);
        pk.z = f2h(acc[i][j][2]); pk.w = f2h(acc[i][j][3]);
        *(ushort4*)&dst[ss] = pk;
      }
    }
  }
}

// ------- out-proj GEMM: fp16 res = acc + resid (single-barrier dbuf) -------
__global__ __launch_bounds__(256) void k_gemm_out(
    const u16* __restrict__ A, const u16* __restrict__ Bw,
    const float* __restrict__ resid, u16* __restrict__ resh){
  __shared__ u16 sA[2*128*32], sB[2*128*32];
  const int t = threadIdx.x, w = t >> 6, l = t & 63;
  const int lr = l & 15, lg = l >> 4;
  const int tn = blockIdx.x & 7, tm = blockIdx.x >> 3;
  const int m0 = tm*128, n0 = tn*128;
  const int wr = (w >> 1)*64, wc = (w & 1)*64;
  f32x4 acc[4][4] = {};

#define GSTAGE(buf, k0_) do { \
    for (int c = 0; c < 2; c++){ \
      int ch  = c*256 + t; \
      int row = ch >> 2; \
      int xb  = (ch & 3) << 4; \
      int col = (k0_) + ((xb ^ ((row & 3) << 4)) >> 1); \
      int ldso = (buf)*8192 + (c*256 + w*64)*16; \
      gl_lds16(A  + (size_t)(m0+row)*En + col, (u16*)((char*)sA + ldso)); \
      gl_lds16(Bw + (size_t)(n0+row)*En + col, (u16*)((char*)sB + ldso)); \
    } } while (0)

  GSTAGE(0, 0);
  __syncthreads();
  for (int kt = 0; kt < En/32; kt++){
    const int cur = kt & 1;
    if (kt < En/32 - 1) GSTAGE(cur^1, (kt+1)*32);
    f16x8 af[4], bf[4];
    #pragma unroll
    for (int i = 0; i < 4; i++){
      int r  = wr + i*16 + lr;
      af[i] = *(const f16x8*)((const char*)sA + cur*8192 + r*64 + ((lg*16) ^ ((r & 3) << 4)));
      int n  = wc + i*16 + lr;
      bf[i] = *(const f16x8*)((const char*)sB + cur*8192 + n*64 + ((lg*16) ^ ((n & 3) << 4)));
    }
    __builtin_amdgcn_s_setprio(1);
    #pragma unroll
    for (int i = 0; i < 4; i++)
      #pragma unroll
      for (int j = 0; j < 4; j++)
        acc[i][j] = mfma16(af[i], bf[j], acc[i][j]);
    __builtin_amdgcn_s_setprio(0);
    __syncthreads();
  }
#undef GSTAGE
  #pragma unroll
  for (int j = 0; j < 4; j++){
    int col = n0 + wc + j*16 + lr;
    #pragma unroll
    for (int i = 0; i < 4; i++){
      int mbase = m0 + wr + i*16 + lg*4;
      #pragma unroll
      for (int r = 0; r < 4; r++){
        size_t o = (size_t)(mbase + r)*En + col;
        resh[o] = f2h(acc[i][j][r] + resid[o]);
      }
    }
  }
}

// -------- flash attention: 8 waves, TQ=128, single-barrier dbuf K/V --------
// qt in HIGH bits of blockIdx: all 8 q-tiles of a (b,h) share one XCD's L2.
__global__ __launch_bounds__(512) void k_attn(
    const u16* __restrict__ qp, const u16* __restrict__ kp,
    const u16* __restrict__ vt, u16* __restrict__ outp){
  __shared__ u16 sK[2][64*64];             // [j][d] rows 128B, XOR-swizzled
  __shared__ u16 sVt[2][64*64];            // [d][j] rows 128B, XOR-swizzled
  __shared__ u16 sP[8][16*72];             // per-wave P[q][k], pad->144B rows
  const int t = threadIdx.x, w = t >> 6, l = t & 63;
  const int lr = l & 15, lg = l >> 4;
  const int qt = blockIdx.x >> 7, hb = blockIdx.x & 127;
  const int h = hb & 15, b = hb >> 4;
  const int q0 = qt*128 + w*16;

  // staging addresses: 512 threads cover one 64x64 fp16 tile per gl_lds each
  const int srow = t >> 3, slot = t & 7, jc = slot ^ (srow & 7);
  const size_t gkbase = (size_t)(b*Sn + srow)*En + h*Dn + jc*8;    // + kt*64*En
  const size_t gvbase = ((size_t)(b*Hn + h)*Dn + srow)*Sn + jc*8;  // + kt*64

#define STAGE(buf, kt_) do { \
    gl_lds16(kp + gkbase + (size_t)(kt_)*64*En, (u16*)((char*)sK[buf] + w*1024)); \
    gl_lds16(vt + gvbase + (kt_)*64,            (u16*)((char*)sVt[buf] + w*1024)); \
  } while (0)

  // Q fragments (B operand: lane holds q-row = q0+lr, k-elems d = lg*8.. )
  size_t qrow = (size_t)(b*Sn + q0 + lr)*En + h*Dn;
  f16x8 qf[2];
  #pragma unroll
  for (int ks = 0; ks < 2; ks++)
    qf[ks] = *(const f16x8*)&qp[qrow + ks*32 + lg*8];
  f32x4 accO[4] = {};
  float mrun = -1e30f, lrun = 0.f;
  u16* P = &sP[w][0];

  STAGE(0, 0);
  __syncthreads();
  for (int kt = 0; kt < Sn/64; kt++){
    const int cur = kt & 1;
    if (kt < Sn/64 - 1) STAGE(cur^1, kt+1);   // overlaps with compute below
    // ---- QK^T swapped: lane holds k = jt*16+lg*4+r for q = q0+lr
    f32x4 s[4] = {};
    __builtin_amdgcn_s_setprio(1);
    #pragma unroll
    for (int ks = 0; ks < 2; ks++)
      #pragma unroll
      for (int jt = 0; jt < 4; jt++){
        int j  = jt*16 + lr;
        int ob = j*128 + ((ks*64 + lg*16) ^ ((j & 7) << 4));
        f16x8 kf = *(const f16x8*)((const char*)sK[cur] + ob);
        s[jt] = mfma16(kf, qf[ks], s[jt]);
      }
    __builtin_amdgcn_s_setprio(0);
    // ---- lane-local softmax (log2 domain; Q pre-scaled by log2e)
    float m16 = fmaxf(fmaxf(fmaxf(s[0][0], s[0][1]), fmaxf(s[0][2], s[0][3])),
                      fmaxf(fmaxf(s[1][0], s[1][1]), fmaxf(s[1][2], s[1][3])));
    m16 = fmaxf(m16, fmaxf(fmaxf(fmaxf(s[2][0], s[2][1]), fmaxf(s[2][2], s[2][3])),
                           fmaxf(fmaxf(s[3][0], s[3][1]), fmaxf(s[3][2], s[3][3]))));
    m16 = fmaxf(m16, __shfl_xor(m16, 16));
    m16 = fmaxf(m16, __shfl_xor(m16, 32));
    bool defer = __all(m16 <= mrun + 8.0f);
    float mn, sc;
    if (defer){ mn = mrun; sc = 1.0f; }
    else { mn = fmaxf(mrun, m16); sc = fexp2(mrun - mn); mrun = mn; }
    float ps = 0.f;
    #pragma unroll
    for (int jt = 0; jt < 4; jt++){
      float p0 = fexp2(s[jt][0] - mn), p1 = fexp2(s[jt][1] - mn);
      float p2 = fexp2(s[jt][2] - mn), p3 = fexp2(s[jt][3] - mn);
      ps += (p0 + p1) + (p2 + p3);
      union { h16x2 h; uint32_t u; } ca, cb;
      ca.h = __builtin_amdgcn_cvt_pkrtz(p0, p1);
      cb.h = __builtin_amdgcn_cvt_pkrtz(p2, p3);
      uint2 pk; pk.x = ca.u; pk.y = cb.u;
      *(uint2*)&P[lr*72 + jt*16 + lg*4] = pk;
    }
    ps += __shfl_xor(ps, 16);
    ps += __shfl_xor(ps, 32);
    lrun = lrun*sc + ps;
    if (!defer){
      #pragma unroll
      for (int r = 0; r < 4; r++){
        float scq = __shfl(sc, lg*4 + r);
        accO[0][r] *= scq; accO[1][r] *= scq;
        accO[2][r] *= scq; accO[3][r] *= scq;
      }
    }
    // ---- PV: O[q][d] += P[q][j] * V^T[d][j]
    __builtin_amdgcn_s_setprio(1);
    #pragma unroll
    for (int js = 0; js < 2; js++){
      f16x8 pa = *(const f16x8*)&P[lr*72 + js*32 + lg*8];
      #pragma unroll
      for (int dt = 0; dt < 4; dt++){
        int d  = dt*16 + lr;
        int ob = d*128 + ((lg*16 + js*64) ^ ((d & 7) << 4));
        f16x8 vb = *(const f16x8*)((const char*)sVt[cur] + ob);
        accO[dt] = mfma16(pa, vb, accO[dt]);
      }
    }
    __builtin_amdgcn_s_setprio(0);
    __syncthreads();   // drains vmcnt (staged next buf) + protects cur buf
  }
#undef STAGE
  // ---- epilogue: normalize rows q = q0 + lg*4 + r
  float inv = 1.0f / lrun;
  float ir[4];
  #pragma unroll
  for (int r = 0; r < 4; r++) ir[r] = __shfl(inv, lg*4 + r);
  #pragma unroll
  for (int dt = 0; dt < 4; dt++){
    int dcol = h*Dn + dt*16 + lr;
    #pragma unroll
    for (int r = 0; r < 4; r++)
      outp[(size_t)(b*Sn + q0 + lg*4 + r)*En + dcol] = f2h(accO[dt][r] * ir[r]);
  }
}

// ---------------- LayerNorm over rows of 1024 (fp16 input) ----------------
__global__ __launch_bounds__(256) void k_ln(const u16* __restrict__ res,
    const float* __restrict__ gamma, const float* __restrict__ beta,
    float* __restrict__ out){
  int row = blockIdx.x, t = threadIdx.x;
  const u16* r = res + (size_t)row*En;
  ushort4 v4 = ((const ushort4*)r)[t];
  float vx = h2f(v4.x), vy = h2f(v4.y), vz = h2f(v4.z), vw = h2f(v4.w);
  float s = vx + vy + vz + vw;
  float q = vx*vx + vy*vy + vz*vz + vw*vw;
  for (int d = 1; d < 64; d <<= 1){ s += __shfl_xor(s, d); q += __shfl_xor(q, d); }
  __shared__ float ss[4], sq[4];
  int w = t >> 6, l = t & 63;
  if (l == 0){ ss[w] = s; sq[w] = q; }
  __syncthreads();
  s = ss[0] + ss[1] + ss[2] + ss[3];
  q = sq[0] + sq[1] + sq[2] + sq[3];
  float mean = s * (1.f/En);
  float var  = q * (1.f/En) - mean*mean;
  float rs   = rsqrtf(var + 1e-6f);
  float4 g = ((const float4*)gamma)[t], bb = ((const float4*)beta)[t];
  float4 o;
  o.x = (vx - mean)*rs*g.x + bb.x;
  o.y = (vy - mean)*rs*g.y + bb.y;
  o.z = (vz - mean)*rs*g.z + bb.z;
  o.w = (vw - mean)*rs*g.w + bb.w;
  ((float4*)(out + (size_t)row*En))[t] = o;
}

extern "C" void kernel_launch(void* const* d_in, const int* in_sizes, int n_in,
                              void* d_out, int out_size, void* d_ws, size_t ws_size,
                              hipStream_t stream){
  (void)in_sizes; (void)n_in; (void)out_size; (void)ws_size;
  const float* X     = (const float*)d_in[0];
  const float* gQ    = (const float*)d_in[1];
  const float* gK    = (const float*)d_in[2];
  const float* Wq    = (const float*)d_in[3];
  const float* Wk    = (const float*)d_in[4];
  const float* Wv    = (const float*)d_in[5];
  const float* Wo    = (const float*)d_in[6];
  const float* gamma = (const float*)d_in[7];
  const float* beta  = (const float*)d_in[8];
  float* out = (float*)d_out;

  char* ws = (char*)d_ws;
  const size_t sz = (size_t)Mn*En*2;           // one fp16 [M][E] tensor (16MB)
  u16* xh = (u16*)(ws + 0*sz);
  u16* qh = (u16*)(ws + 1*sz);
  u16* kh = (u16*)(ws + 2*sz);
  u16* vb = (u16*)(ws + 3*sz);                 // V^T [B][H][D][S]
  u16* ao = (u16*)(ws + 4*sz);
  u16* res = (u16*)(ws + 0*sz);                // fp16, overlays xh (dead by then)
  u16* wq = (u16*)(ws + 5*sz);                 // [3072][1024] fp16: Wq^T|Wk^T|Wv^T
  u16* wk = wq + (size_t)En*En;
  u16* wv = wk + (size_t)En*En;
  u16* wo = wv + (size_t)En*En;

  // fused prep: X cvt (8192 blocks) + Wo cvt (1024) + QKV transpose (3072)
  k_prep<<<12288, 256, 0, stream>>>(X, Wq, Wk, Wv, Wo, xh, wq, wk, wv, wo);
  // fused QKV: Q gate*2/sqrt(64)*log2(e), K gate*2, V -> per-head V^T
  k_gemm_qkv<<<(Mn/128)*(3*En/128), 256, 0, stream>>>(xh, wq, gQ, gK, qh, kh, vb);
  k_attn<<<(Sn/128)*Hn*Bn, 512, 0, stream>>>(qh, kh, vb, ao);
  k_gemm_out<<<(Mn/128)*(En/128), 256, 0, stream>>>(ao, wo, X, res);
  k_ln<<<Mn, 256, 0, stream>>>(res, gamma, beta, out);
}

// Round 8
// 263.639 us; speedup vs baseline: 1.6570x; 1.0494x over previous
//
#include <hip/hip_runtime.h>
#include <stdint.h>

#define Bn 8
#define Sn 1024
#define En 1024
#define Hn 16
#define Dn 64
#define Mn (Bn*Sn)

typedef unsigned short u16;
typedef _Float16 f16;
typedef _Float16 f16x8 __attribute__((ext_vector_type(8)));
typedef __fp16   h16x2 __attribute__((ext_vector_type(2)));
typedef float    f32x4 __attribute__((ext_vector_type(4)));

#define VMCNT(n) asm volatile("s_waitcnt vmcnt(" #n ")" ::: "memory")
#define CFENCE() asm volatile("" ::: "memory")

static __device__ __forceinline__ u16 f2h(float x){
  f16 h = (f16)x;                       // native RNE cast -> v_cvt_f16_f32
  union { f16 h; u16 u; } c; c.h = h; return c.u;
}
static __device__ __forceinline__ float h2f(u16 u){
  union { u16 u; f16 h; } c; c.u = u; return (float)c.h;
}
static __device__ __forceinline__ float fexp2(float x){
  float r; asm("v_exp_f32 %0, %1" : "=v"(r) : "v"(x)); return r;
}
static __device__ __forceinline__ f32x4 mfma16(f16x8 a, f16x8 b, f32x4 c){
  return __builtin_amdgcn_mfma_f32_16x16x32_f16(a, b, c, 0, 0, 0);
}
static __device__ __forceinline__ void gl_lds16(const u16* g, u16* l){
  __builtin_amdgcn_global_load_lds((__attribute__((address_space(1))) void*)g,
                                   (__attribute__((address_space(3))) void*)l, 16, 0, 0);
}

// ------------- fused prep: X->fp16 | Wo->fp16 | Wq/Wk/Wv transpose ----------
// blocks [0,8192): cvt X ; [8192,9216): cvt Wo ; [9216,12288): transpose QKV
__global__ __launch_bounds__(256) void k_prep(const float* __restrict__ X,
    const float* __restrict__ Wq, const float* __restrict__ Wk,
    const float* __restrict__ Wv, const float* __restrict__ Wo,
    u16* __restrict__ xh, u16* __restrict__ wq, u16* __restrict__ wk,
    u16* __restrict__ wv, u16* __restrict__ wo){
  __shared__ float tsh[32][33];
  const int bid = blockIdx.x, tid = threadIdx.x;
  if (bid < 9216){
    const float* src = (bid < 8192) ? X : Wo;
    u16* dst = (bid < 8192) ? xh : wo;
    int i = (bid < 8192 ? bid : bid - 8192)*256 + tid;
    float4 v = ((const float4*)src)[i];
    ushort4 h; h.x = f2h(v.x); h.y = f2h(v.y); h.z = f2h(v.z); h.w = f2h(v.w);
    ((ushort4*)dst)[i] = h;
  } else {
    int pb = bid - 9216;
    int sel = pb >> 10, inner = pb & 1023;
    int bx = inner & 31, by = inner >> 5;
    int tx = tid & 31, ty = tid >> 5;
    const float* W = (sel == 0) ? Wq : (sel == 1) ? Wk : Wv;
    u16* D = (sel == 0) ? wq : (sel == 1) ? wk : wv;
    for (int i = 0; i < 32; i += 8)
      tsh[ty+i][tx] = W[(size_t)(by*32+ty+i)*En + bx*32+tx];
    __syncthreads();
    for (int i = 0; i < 32; i += 8)
      D[(size_t)(bx*32+ty+i)*En + by*32+tx] = f2h(tsh[tx][ty+i]);
  }
}

// ---- fused QKV projection GEMM: B = [3072][1024] (Wq^T|Wk^T|Wv^T stacked) ----
// BK=64, 2-buf, counted vmcnt(8), raw barriers, 128B-row XOR swizzle (m201)
__global__ __launch_bounds__(256) void k_gemm_qkv(
    const u16* __restrict__ A, const u16* __restrict__ Bw,
    const float* __restrict__ gQ, const float* __restrict__ gK,
    u16* __restrict__ Cq, u16* __restrict__ Ck, u16* __restrict__ Vt){
  __shared__ u16 sA[2*128*64], sB[2*128*64];   // 2 x 16KB each
  const int t = threadIdx.x, w = t >> 6, l = t & 63;
  const int lr = l & 15, lg = l >> 4;
  const int tn = blockIdx.x % 24, tm = blockIdx.x / 24;
  const int m0 = tm*128, n0 = tn*128;
  const int wr = (w >> 1)*64, wc = (w & 1)*64;
  f32x4 acc[4][4] = {};

  // stage one 128x64 fp16 tile per matrix: 4 rounds x 256 chunks of 16B.
  // chunk ch -> row=ch>>3, slot8=ch&7; source col pre-swizzled so that
  // linear LDS dest + XOR read = consistent (guideline 21).
#define GSTAGE(buf, k0_) do { \
    for (int c = 0; c < 4; c++){ \
      int ch  = c*256 + t; \
      int row = ch >> 3; \
      int jc  = (ch & 7) ^ (row & 7); \
      int ldso = (buf)*16384 + (c*256 + w*64)*16; \
      gl_lds16(A  + (size_t)(m0+row)*En + (k0_) + jc*8, (u16*)((char*)sA + ldso)); \
      gl_lds16(Bw + (size_t)(n0+row)*En + (k0_) + jc*8, (u16*)((char*)sB + ldso)); \
    } } while (0)

  GSTAGE(0, 0);
  for (int kt = 0; kt < En/64; kt++){
    const int cur = kt & 1;
    if (kt < En/64 - 1){ GSTAGE(cur^1, (kt+1)*64); VMCNT(8); }
    else               { VMCNT(0); }
    __builtin_amdgcn_s_barrier();   // buf cur fully staged by all waves
    CFENCE();
    #pragma unroll
    for (int ks = 0; ks < 2; ks++){
      f16x8 af[4], bf[4];
      #pragma unroll
      for (int i = 0; i < 4; i++){
        int r  = wr + i*16 + lr;
        af[i] = *(const f16x8*)((const char*)sA + cur*16384 + r*128 + ((ks*64 + lg*16) ^ ((r & 7) << 4)));
        int n  = wc + i*16 + lr;
        bf[i] = *(const f16x8*)((const char*)sB + cur*16384 + n*128 + ((ks*64 + lg*16) ^ ((n & 7) << 4)));
      }
      __builtin_amdgcn_s_setprio(1);
      #pragma unroll
      for (int i = 0; i < 4; i++)
        #pragma unroll
        for (int j = 0; j < 4; j++)
          acc[i][j] = mfma16(af[i], bf[j], acc[i][j]);
      __builtin_amdgcn_s_setprio(0);
    }
    CFENCE();
    __builtin_amdgcn_s_barrier();   // all waves done reading buf cur
  }
#undef GSTAGE
  const int bb = m0 >> 10;   // batch (BM=128 never crosses batch boundary)
  const int sel = n0 >> 10;  // 0=Q 1=K 2=V (uniform per block)
  if (sel < 2){
    const float* gate = sel ? gK : gQ;
    const float gs = sel ? 2.0f : 0.25f*1.4426950408889634f;
    u16* C = sel ? Ck : Cq;
    #pragma unroll
    for (int j = 0; j < 4; j++){
      int col = (n0 & 1023) + wc + j*16 + lr;
      float g = gate[bb*En + col] * gs;
      #pragma unroll
      for (int i = 0; i < 4; i++){
        int mbase = m0 + wr + i*16 + lg*4;
        #pragma unroll
        for (int r = 0; r < 4; r++)
          C[(size_t)(mbase + r)*En + col] = f2h(acc[i][j][r] * g);
      }
    }
  } else {
    const int s0 = (m0 & 1023) + wr;
    #pragma unroll
    for (int j = 0; j < 4; j++){
      int nn = (n0 - 2048) + wc + j*16 + lr;
      int hh = nn >> 6, d = nn & 63;
      u16* dst = Vt + ((size_t)(bb*Hn + hh)*Dn + d)*Sn;
      #pragma unroll
      for (int i = 0; i < 4; i++){
        int ss = s0 + i*16 + lg*4;
        ushort4 pk;
        pk.x = f2h(acc[i][j][0]); pk.y = f2h(acc[i][j][1]);
        pk.z = f2h(acc[i][j][2]); pk.w = f2h(acc[i][j][3]);
        *(ushort4*)&dst[ss] = pk;
      }
    }
  }
}

// ------- out-proj GEMM: fp16 res = acc + resid (same BK=64 structure) -------
__global__ __launch_bounds__(256) void k_gemm_out(
    const u16* __restrict__ A, const u16* __restrict__ Bw,
    const float* __restrict__ resid, u16* __restrict__ resh){
  __shared__ u16 sA[2*128*64], sB[2*128*64];
  const int t = threadIdx.x, w = t >> 6, l = t & 63;
  const int lr = l & 15, lg = l >> 4;
  const int tn = blockIdx.x & 7, tm = blockIdx.x >> 3;
  const int m0 = tm*128, n0 = tn*128;
  const int wr = (w >> 1)*64, wc = (w & 1)*64;
  f32x4 acc[4][4] = {};

#define GSTAGE(buf, k0_) do { \
    for (int c = 0; c < 4; c++){ \
      int ch  = c*256 + t; \
      int row = ch >> 3; \
      int jc  = (ch & 7) ^ (row & 7); \
      int ldso = (buf)*16384 + (c*256 + w*64)*16; \
      gl_lds16(A  + (size_t)(m0+row)*En + (k0_) + jc*8, (u16*)((char*)sA + ldso)); \
      gl_lds16(Bw + (size_t)(n0+row)*En + (k0_) + jc*8, (u16*)((char*)sB + ldso)); \
    } } while (0)

  GSTAGE(0, 0);
  for (int kt = 0; kt < En/64; kt++){
    const int cur = kt & 1;
    if (kt < En/64 - 1){ GSTAGE(cur^1, (kt+1)*64); VMCNT(8); }
    else               { VMCNT(0); }
    __builtin_amdgcn_s_barrier();
    CFENCE();
    #pragma unroll
    for (int ks = 0; ks < 2; ks++){
      f16x8 af[4], bf[4];
      #pragma unroll
      for (int i = 0; i < 4; i++){
        int r  = wr + i*16 + lr;
        af[i] = *(const f16x8*)((const char*)sA + cur*16384 + r*128 + ((ks*64 + lg*16) ^ ((r & 7) << 4)));
        int n  = wc + i*16 + lr;
        bf[i] = *(const f16x8*)((const char*)sB + cur*16384 + n*128 + ((ks*64 + lg*16) ^ ((n & 7) << 4)));
      }
      __builtin_amdgcn_s_setprio(1);
      #pragma unroll
      for (int i = 0; i < 4; i++)
        #pragma unroll
        for (int j = 0; j < 4; j++)
          acc[i][j] = mfma16(af[i], bf[j], acc[i][j]);
      __builtin_amdgcn_s_setprio(0);
    }
    CFENCE();
    __builtin_amdgcn_s_barrier();
  }
#undef GSTAGE
  #pragma unroll
  for (int j = 0; j < 4; j++){
    int col = n0 + wc + j*16 + lr;
    #pragma unroll
    for (int i = 0; i < 4; i++){
      int mbase = m0 + wr + i*16 + lg*4;
      #pragma unroll
      for (int r = 0; r < 4; r++){
        size_t o = (size_t)(mbase + r)*En + col;
        resh[o] = f2h(acc[i][j][r] + resid[o]);
      }
    }
  }
}

// -------- flash attention: 8 waves, TQ=128, single-barrier dbuf K/V --------
// qt in HIGH bits of blockIdx: all 8 q-tiles of a (b,h) share one XCD's L2.
__global__ __launch_bounds__(512) void k_attn(
    const u16* __restrict__ qp, const u16* __restrict__ kp,
    const u16* __restrict__ vt, u16* __restrict__ outp){
  __shared__ u16 sK[2][64*64];             // [j][d] rows 128B, XOR-swizzled
  __shared__ u16 sVt[2][64*64];            // [d][j] rows 128B, XOR-swizzled
  __shared__ u16 sP[8][16*72];             // per-wave P[q][k], pad->144B rows
  const int t = threadIdx.x, w = t >> 6, l = t & 63;
  const int lr = l & 15, lg = l >> 4;
  const int qt = blockIdx.x >> 7, hb = blockIdx.x & 127;
  const int h = hb & 15, b = hb >> 4;
  const int q0 = qt*128 + w*16;

  // staging addresses: 512 threads cover one 64x64 fp16 tile per gl_lds each
  const int srow = t >> 3, slot = t & 7, jc = slot ^ (srow & 7);
  const size_t gkbase = (size_t)(b*Sn + srow)*En + h*Dn + jc*8;    // + kt*64*En
  const size_t gvbase = ((size_t)(b*Hn + h)*Dn + srow)*Sn + jc*8;  // + kt*64

#define STAGE(buf, kt_) do { \
    gl_lds16(kp + gkbase + (size_t)(kt_)*64*En, (u16*)((char*)sK[buf] + w*1024)); \
    gl_lds16(vt + gvbase + (kt_)*64,            (u16*)((char*)sVt[buf] + w*1024)); \
  } while (0)

  // Q fragments (B operand: lane holds q-row = q0+lr, k-elems d = lg*8.. )
  size_t qrow = (size_t)(b*Sn + q0 + lr)*En + h*Dn;
  f16x8 qf[2];
  #pragma unroll
  for (int ks = 0; ks < 2; ks++)
    qf[ks] = *(const f16x8*)&qp[qrow + ks*32 + lg*8];
  f32x4 accO[4] = {};
  float mrun = -1e30f, lrun = 0.f;
  u16* P = &sP[w][0];

  STAGE(0, 0);
  __syncthreads();
  for (int kt = 0; kt < Sn/64; kt++){
    const int cur = kt & 1;
    if (kt < Sn/64 - 1) STAGE(cur^1, kt+1);   // overlaps with compute below
    // ---- QK^T swapped: lane holds k = jt*16+lg*4+r for q = q0+lr
    f32x4 s[4] = {};
    __builtin_amdgcn_s_setprio(1);
    #pragma unroll
    for (int ks = 0; ks < 2; ks++)
      #pragma unroll
      for (int jt = 0; jt < 4; jt++){
        int j  = jt*16 + lr;
        int ob = j*128 + ((ks*64 + lg*16) ^ ((j & 7) << 4));
        f16x8 kf = *(const f16x8*)((const char*)sK[cur] + ob);
        s[jt] = mfma16(kf, qf[ks], s[jt]);
      }
    __builtin_amdgcn_s_setprio(0);
    // ---- lane-local softmax (log2 domain; Q pre-scaled by log2e)
    float m16 = fmaxf(fmaxf(fmaxf(s[0][0], s[0][1]), fmaxf(s[0][2], s[0][3])),
                      fmaxf(fmaxf(s[1][0], s[1][1]), fmaxf(s[1][2], s[1][3])));
    m16 = fmaxf(m16, fmaxf(fmaxf(fmaxf(s[2][0], s[2][1]), fmaxf(s[2][2], s[2][3])),
                           fmaxf(fmaxf(s[3][0], s[3][1]), fmaxf(s[3][2], s[3][3]))));
    m16 = fmaxf(m16, __shfl_xor(m16, 16));
    m16 = fmaxf(m16, __shfl_xor(m16, 32));
    bool defer = __all(m16 <= mrun + 8.0f);
    float mn, sc;
    if (defer){ mn = mrun; sc = 1.0f; }
    else { mn = fmaxf(mrun, m16); sc = fexp2(mrun - mn); mrun = mn; }
    float ps = 0.f;
    #pragma unroll
    for (int jt = 0; jt < 4; jt++){
      float p0 = fexp2(s[jt][0] - mn), p1 = fexp2(s[jt][1] - mn);
      float p2 = fexp2(s[jt][2] - mn), p3 = fexp2(s[jt][3] - mn);
      ps += (p0 + p1) + (p2 + p3);
      union { h16x2 h; uint32_t u; } ca, cb;
      ca.h = __builtin_amdgcn_cvt_pkrtz(p0, p1);
      cb.h = __builtin_amdgcn_cvt_pkrtz(p2, p3);
      uint2 pk; pk.x = ca.u; pk.y = cb.u;
      *(uint2*)&P[lr*72 + jt*16 + lg*4] = pk;
    }
    ps += __shfl_xor(ps, 16);
    ps += __shfl_xor(ps, 32);
    lrun = lrun*sc + ps;
    if (!defer){
      #pragma unroll
      for (int r = 0; r < 4; r++){
        float scq = __shfl(sc, lg*4 + r);
        accO[0][r] *= scq; accO[1][r] *= scq;
        accO[2][r] *= scq; accO[3][r] *= scq;
      }
    }
    // ---- PV: O[q][d] += P[q][j] * V^T[d][j]
    __builtin_amdgcn_s_setprio(1);
    #pragma unroll
    for (int js = 0; js < 2; js++){
      f16x8 pa = *(const f16x8*)&P[lr*72 + js*32 + lg*8];
      #pragma unroll
      for (int dt = 0; dt < 4; dt++){
        int d  = dt*16 + lr;
        int ob = d*128 + ((lg*16 + js*64) ^ ((d & 7) << 4));
        f16x8 vb = *(const f16x8*)((const char*)sVt[cur] + ob);
        accO[dt] = mfma16(pa, vb, accO[dt]);
      }
    }
    __builtin_amdgcn_s_setprio(0);
    __syncthreads();   // drains vmcnt (staged next buf) + protects cur buf
  }
#undef STAGE
  // ---- epilogue: normalize rows q = q0 + lg*4 + r
  float inv = 1.0f / lrun;
  float ir[4];
  #pragma unroll
  for (int r = 0; r < 4; r++) ir[r] = __shfl(inv, lg*4 + r);
  #pragma unroll
  for (int dt = 0; dt < 4; dt++){
    int dcol = h*Dn + dt*16 + lr;
    #pragma unroll
    for (int r = 0; r < 4; r++)
      outp[(size_t)(b*Sn + q0 + lg*4 + r)*En + dcol] = f2h(accO[dt][r] * ir[r]);
  }
}

// ---------------- LayerNorm over rows of 1024 (fp16 input) ----------------
__global__ __launch_bounds__(256) void k_ln(const u16* __restrict__ res,
    const float* __restrict__ gamma, const float* __restrict__ beta,
    float* __restrict__ out){
  int row = blockIdx.x, t = threadIdx.x;
  const u16* r = res + (size_t)row*En;
  ushort4 v4 = ((const ushort4*)r)[t];
  float vx = h2f(v4.x), vy = h2f(v4.y), vz = h2f(v4.z), vw = h2f(v4.w);
  float s = vx + vy + vz + vw;
  float q = vx*vx + vy*vy + vz*vz + vw*vw;
  for (int d = 1; d < 64; d <<= 1){ s += __shfl_xor(s, d); q += __shfl_xor(q, d); }
  __shared__ float ss[4], sq[4];
  int w = t >> 6, l = t & 63;
  if (l == 0){ ss[w] = s; sq[w] = q; }
  __syncthreads();
  s = ss[0] + ss[1] + ss[2] + ss[3];
  q = sq[0] + sq[1] + sq[2] + sq[3];
  float mean = s * (1.f/En);
  float var  = q * (1.f/En) - mean*mean;
  float rs   = rsqrtf(var + 1e-6f);
  float4 g = ((const float4*)gamma)[t], bb = ((const float4*)beta)[t];
  float4 o;
  o.x = (vx - mean)*rs*g.x + bb.x;
  o.y = (vy - mean)*rs*g.y + bb.y;
  o.z = (vz - mean)*rs*g.z + bb.z;
  o.w = (vw - mean)*rs*g.w + bb.w;
  ((float4*)(out + (size_t)row*En))[t] = o;
}

extern "C" void kernel_launch(void* const* d_in, const int* in_sizes, int n_in,
                              void* d_out, int out_size, void* d_ws, size_t ws_size,
                              hipStream_t stream){
  (void)in_sizes; (void)n_in; (void)out_size; (void)ws_size;
  const float* X     = (const float*)d_in[0];
  const float* gQ    = (const float*)d_in[1];
  const float* gK    = (const float*)d_in[2];
  const float* Wq    = (const float*)d_in[3];
  const float* Wk    = (const float*)d_in[4];
  const float* Wv    = (const float*)d_in[5];
  const float* Wo    = (const float*)d_in[6];
  const float* gamma = (const float*)d_in[7];
  const float* beta  = (const float*)d_in[8];
  float* out = (float*)d_out;

  char* ws = (char*)d_ws;
  const size_t sz = (size_t)Mn*En*2;           // one fp16 [M][E] tensor (16MB)
  u16* xh = (u16*)(ws + 0*sz);
  u16* qh = (u16*)(ws + 1*sz);
  u16* kh = (u16*)(ws + 2*sz);
  u16* vb = (u16*)(ws + 3*sz);                 // V^T [B][H][D][S]
  u16* ao = (u16*)(ws + 4*sz);
  u16* res = (u16*)(ws + 0*sz);                // fp16, overlays xh (dead by then)
  u16* wq = (u16*)(ws + 5*sz);                 // [3072][1024] fp16: Wq^T|Wk^T|Wv^T
  u16* wk = wq + (size_t)En*En;
  u16* wv = wk + (size_t)En*En;
  u16* wo = wv + (size_t)En*En;

  // fused prep: X cvt (8192 blocks) + Wo cvt (1024) + QKV transpose (3072)
  k_prep<<<12288, 256, 0, stream>>>(X, Wq, Wk, Wv, Wo, xh, wq, wk, wv, wo);
  // fused QKV: Q gate*2/sqrt(64)*log2(e), K gate*2, V -> per-head V^T
  k_gemm_qkv<<<(Mn/128)*(3*En/128), 256, 0, stream>>>(xh, wq, gQ, gK, qh, kh, vb);
  k_attn<<<(Sn/128)*Hn*Bn, 512, 0, stream>>>(qh, kh, vb, ao);
  k_gemm_out<<<(Mn/128)*(En/128), 256, 0, stream>>>(ao, wo, X, res);
  k_ln<<<Mn, 256, 0, stream>>>(res, gamma, beta, out);
}